// Round 5
// baseline (193.551 us; speedup 1.0000x reference)
//
#include <hip/hip_runtime.h>
#include <math.h>

#define SIN_ 128
#define TEMB_ 512
#define EMB_ 1024
#define S_ 64
#define B_ 4
#define T_ 4096
#define NROW (B_*T_)          // 16384
#define L_ 32                 // scan chunk length
#define NC_ (T_/L_)           // 128 chunks per batch row

#define GK 32                 // K-rows per partial block
#define NSL 32                // column slices per region (slice = 512 f4 = 2048 floats = 8 KB)
#define NCH 16                // W chunks (512/GK)
#define NGCH 4                // gate chunks (128/GK)

// workspace layout (float offsets)
#define WS_T1     0
#define WS_T2     512
#define WS_DELTA  1024
#define WS_ABAR   1088
#define WS_EL     1152
#define WS_FAC    1216                    // L_*S_ = 2048
#define WS_D      3264                    // 1024
#define WS_BMT    4288                    // BmT[e][s] = 65536
#define WS_CT     69824                   // CT[s][e]  = 65536
#define WS_PD     135360                  // 16*1024 f32
#define WS_PDG    151744                  // 4*1024 f32
#define WS_PA     155840                  // A final sums: [64] + gate [64]
#define WS_PDL    156160                  // dl final sums: [64] + gate [64]
#define WS_PBF    156480                  // bf16 partials (2,621,440 bf16 = 1,310,720 float slots)
// W  partials: ushort4 idx 0      .. 524288   ([2][32][16][512])
// G  partials: ushort4 idx 524288 .. 655360   ([2][32][4][512])
#define WS_HLOC   156480                  // overlaps PBF (PBF dead after finalize)
#define WS_CHEND  1205056
#define WS_CARRY  1237824

__device__ __forceinline__ float sigmoidf_(float x){ return 1.f/(1.f+expf(-x)); }
__device__ __forceinline__ float softplusf_(float x){ return x>20.f ? x : log1pf(expf(x)); }
__device__ __forceinline__ float4 sig4_(float4 g){
  float4 r; r.x=sigmoidf_(g.x); r.y=sigmoidf_(g.y); r.z=sigmoidf_(g.z); r.w=sigmoidf_(g.w); return r;
}
__device__ __forceinline__ unsigned short f2bf(float x){
  unsigned int u = __float_as_uint(x);
  unsigned int r = (u + 0x7FFFu + ((u>>16)&1u)) >> 16;
  return (unsigned short)r;
}
__device__ __forceinline__ ushort4 pack4(float4 v){
  return make_ushort4(f2bf(v.x),f2bf(v.y),f2bf(v.z),f2bf(v.w));
}
__device__ __forceinline__ float bf2f(unsigned short h){
  return __uint_as_float(((unsigned int)h)<<16);
}
__device__ __forceinline__ void gll16(const void* g, void* l){
  __builtin_amdgcn_global_load_lds((const __attribute__((address_space(1))) void*)g,
                                   (__attribute__((address_space(3))) void*)l, 16, 0, 0);
}
#define WAITV(N) asm volatile("s_waitcnt vmcnt(" #N ")" ::: "memory")

// ---- t1 = silu(te @ W1 + b1) ----
__global__ void k_t1(const float* __restrict__ te, const float* __restrict__ W1,
                     const float* __restrict__ b1, float* __restrict__ ws){
  __shared__ float ste[SIN_];
  int tid = threadIdx.x;                 // 64 threads, 8 blocks
  ste[tid] = te[tid]; ste[tid+64] = te[tid+64];
  __syncthreads();
  int j = blockIdx.x*64 + tid;
  float a = b1[j];
  #pragma unroll 16
  for (int i=0;i<SIN_;i++) a += ste[i]*W1[i*TEMB_ + j];
  ws[WS_T1 + j] = a * sigmoidf_(a);
}

// ---- t2 = t1 @ W2 + b2 ----
__global__ __launch_bounds__(512) void k_t2(const float* __restrict__ W2,
                                            const float* __restrict__ b2,
                                            float* __restrict__ ws){
  __shared__ float st1[TEMB_];
  __shared__ float red[8][64];
  int tid = threadIdx.x;
  st1[tid] = ws[WS_T1 + tid];
  __syncthreads();
  int jl = tid & 63, kc = tid >> 6;
  int j = blockIdx.x*64 + jl;
  float p = 0.f;
  #pragma unroll 8
  for (int i=0;i<64;i++){
    int k = kc*64 + i;
    p += st1[k]*W2[k*TEMB_ + j];
  }
  red[kc][jl] = p;
  __syncthreads();
  if (tid < 64){
    float a = b2[blockIdx.x*64 + tid];
    #pragma unroll
    for (int c=0;c<8;c++) a += red[c][tid];
    ws[WS_T2 + blockIdx.x*64 + tid] = a;
  }
}

// ---- split-K partial sums, global_load_lds ring pipeline ----
// blocks 0..1023    : B/C W-part. r=bb>>9, j=(bb&511)>>4 (32 slices), c=bb&15.
// blocks 1024..1279 : B/C gates.  g=bb-1024: r=g>>7, j=(g&127)>>2, cg=g&3.
// blocks 1280..1295 : D W-part;  1296..1299: D gates; 1300: A; 1301: dl
__global__ __launch_bounds__(256) void k_partial(
    const float* __restrict__ te,
    const float* __restrict__ WB, const float* __restrict__ MB,
    const float* __restrict__ WC, const float* __restrict__ MC,
    const float* __restrict__ WD, const float* __restrict__ MD,
    const float* __restrict__ WA, const float* __restrict__ MA,
    const float* __restrict__ Wdl, const float* __restrict__ Mdl,
    float* __restrict__ ws){
  __shared__ float ring[4][2048];        // 4 slots x 8 KB
  __shared__ float st2[TEMB_];
  __shared__ float ste[SIN_];
  int tid = threadIdx.x;
  st2[tid] = ws[WS_T2 + tid];
  st2[tid+256] = ws[WS_T2 + tid + 256];
  if (tid < SIN_) ste[tid] = te[tid];
  __syncthreads();                       // drains vmcnt -> clean slate for ring
  unsigned short* pbf = (unsigned short*)(ws + WS_PBF);
  ushort4* pbf4 = (ushort4*)pbf;
  int bb = blockIdx.x;
  if (bb < 1280){
    const float4* W4; const float* coef; size_t row0; ushort4* dst;
    int j;
    if (bb < 1024){
      int r = bb>>9, rem = bb&511, c = rem&15; j = rem>>4;
      W4 = (const float4*)(r ? WC : WB);
      coef = st2 + c*GK; row0 = (size_t)c*GK;
      dst = pbf4 + ((size_t)(r*NSL+j)*NCH + c)*512;
    } else {
      int g = bb-1024, r = g>>7, rem = g&127, cg = rem&3; j = rem>>2;
      W4 = (const float4*)(r ? MC : MB);
      coef = ste + cg*GK; row0 = (size_t)cg*GK;
      dst = pbf4 + 524288 + ((size_t)(r*NSL+j)*NGCH + cg)*512;
    }
    int w = tid>>6, lane = tid&63;
    char* rbase = (char*)&ring[0][0];
    const int j512 = j*512;
    // stage row 'row' into ring slot 'slot' (8 KB = 2 x 1KB per wave)
    auto stage = [&](int row, int slot){
      const float4* gp = W4 + (row0 + row)*16384 + j512 + (w*128 + lane);
      char* lp = rbase + slot*8192 + w*2048;
      gll16(gp,      lp);
      gll16(gp + 64, lp + 1024);
    };
    #pragma unroll
    for (int p0=0;p0<4;p0++) stage(p0, p0);
    float4 a0={0,0,0,0}, a1={0,0,0,0};
    for (int k=0;k<GK;k++){
      int slot = k & 3;
      int rem = GK-1-k;
      if (rem>=3) WAITV(6); else if (rem==2) WAITV(4); else if (rem==1) WAITV(2); else WAITV(0);
      __builtin_amdgcn_s_barrier();
      asm volatile("" ::: "memory");
      const char* rb = rbase + slot*8192;
      float4 w0 = *(const float4*)(rb + tid*16);
      float4 w1 = *(const float4*)(rb + 4096 + tid*16);
      float cv = coef[k];
      a0.x=fmaf(cv,w0.x,a0.x); a0.y=fmaf(cv,w0.y,a0.y); a0.z=fmaf(cv,w0.z,a0.z); a0.w=fmaf(cv,w0.w,a0.w);
      a1.x=fmaf(cv,w1.x,a1.x); a1.y=fmaf(cv,w1.y,a1.y); a1.z=fmaf(cv,w1.z,a1.z); a1.w=fmaf(cv,w1.w,a1.w);
      asm volatile("s_waitcnt lgkmcnt(0)" ::: "memory");
      __builtin_amdgcn_s_barrier();
      if (k+4 < GK) stage(k+4, slot);
    }
    dst[tid]     = pack4(a0);
    dst[tid+256] = pack4(a1);
  } else if (bb < 1296){
    int c = bb-1280;
    const float4* base = (const float4*)WD + (size_t)(c*GK)*256 + tid;
    const float* coef = st2 + c*GK;
    float4 a={0,0,0,0};
    #pragma unroll 4
    for (int k=0;k<GK;k++){
      float4 w = base[(size_t)k*256];
      float cv = coef[k];
      a.x=fmaf(cv,w.x,a.x); a.y=fmaf(cv,w.y,a.y); a.z=fmaf(cv,w.z,a.z); a.w=fmaf(cv,w.w,a.w);
    }
    ((float4*)(ws + WS_PD))[c*256 + tid] = a;
  } else if (bb < 1300){
    int cg = bb-1296;
    const float4* base = (const float4*)MD + (size_t)(cg*GK)*256 + tid;
    const float* coef = ste + cg*GK;
    float4 a={0,0,0,0};
    #pragma unroll 4
    for (int k=0;k<GK;k++){
      float4 w = base[(size_t)k*256];
      float cv = coef[k];
      a.x=fmaf(cv,w.x,a.x); a.y=fmaf(cv,w.y,a.y); a.z=fmaf(cv,w.z,a.z); a.w=fmaf(cv,w.w,a.w);
    }
    ((float4*)(ws + WS_PDG))[cg*256 + tid] = a;
  } else {
    const float* Wm = (bb==1300) ? WA : Wdl;
    const float* Mm = (bb==1300) ? MA : Mdl;
    int outbase = (bb==1300) ? WS_PA : WS_PDL;
    __shared__ float red[16][68];
    int q = tid&15, kr = tid>>4;
    float4 acc={0,0,0,0};
    const float4* W4 = (const float4*)Wm;
    #pragma unroll 4
    for (int it=0; it<32; ++it){
      int k = it*16 + kr;
      float4 w = W4[k*16 + q];
      float cv = st2[k];
      acc.x=fmaf(cv,w.x,acc.x); acc.y=fmaf(cv,w.y,acc.y); acc.z=fmaf(cv,w.z,acc.z); acc.w=fmaf(cv,w.w,acc.w);
    }
    red[kr][4*q+0]=acc.x; red[kr][4*q+1]=acc.y; red[kr][4*q+2]=acc.z; red[kr][4*q+3]=acc.w;
    __syncthreads();
    if (tid < 64){
      float s = 0.f;
      #pragma unroll
      for (int g=0;g<16;g++) s += red[g][tid];
      ws[outbase + tid] = s;
    }
    __syncthreads();
    float4 gac={0,0,0,0};
    const float4* M4 = (const float4*)Mm;
    #pragma unroll 4
    for (int it=0; it<8; ++it){
      int k = it*16 + kr;
      float4 w = M4[k*16 + q];
      float cv = ste[k];
      gac.x=fmaf(cv,w.x,gac.x); gac.y=fmaf(cv,w.y,gac.y); gac.z=fmaf(cv,w.z,gac.z); gac.w=fmaf(cv,w.w,gac.w);
    }
    red[kr][4*q+0]=gac.x; red[kr][4*q+1]=gac.y; red[kr][4*q+2]=gac.z; red[kr][4*q+3]=gac.w;
    __syncthreads();
    if (tid < 64){
      float s = 0.f;
      #pragma unroll
      for (int g=0;g<16;g++) s += red[g][tid];
      ws[outbase + 64 + tid] = s;
    }
  }
}

// ---- finalize: reduce bf16 partials, bias+gate, write BmT/CT/D; A/delta/fac ----
__global__ __launch_bounds__(256) void k_finalize(
    const float* __restrict__ bB, const float* __restrict__ mB,
    const float* __restrict__ bC, const float* __restrict__ mC,
    const float* __restrict__ bD, const float* __restrict__ mD,
    const float* __restrict__ bA_, const float* __restrict__ mA_,
    const float* __restrict__ bdl, const float* __restrict__ mdl,
    float* __restrict__ ws){
  int tid = threadIdx.x, bb = blockIdx.x;
  const ushort4* pbf4 = (const ushort4*)(ws + WS_PBF);
  if (bb < 128){
    int r = bb>>6;
    int q = (bb&63)*256 + tid;        // f4 idx within region [0,16384)
    int j = q>>9, p = q&511;
    float4 a = {0,0,0,0};
    size_t wbase = ((size_t)(r*NSL+j)*NCH)*512 + p;
    #pragma unroll
    for (int c=0;c<NCH;c++){
      ushort4 v = pbf4[wbase + (size_t)c*512];
      a.x += bf2f(v.x); a.y += bf2f(v.y); a.z += bf2f(v.z); a.w += bf2f(v.w);
    }
    float4 g = {0,0,0,0};
    size_t gbase = 524288 + ((size_t)(r*NSL+j)*NGCH)*512 + p;
    #pragma unroll
    for (int cg=0;cg<NGCH;cg++){
      ushort4 v = pbf4[gbase + (size_t)cg*512];
      g.x += bf2f(v.x); g.y += bf2f(v.y); g.z += bf2f(v.z); g.w += bf2f(v.w);
    }
    if (r == 0){
      float4 b4 = ((const float4*)bB)[q];
      float4 m4 = ((const float4*)mB)[q];
      float4 sg = sig4_(make_float4(g.x+m4.x, g.y+m4.y, g.z+m4.z, g.w+m4.w));
      float4 v = make_float4((a.x+b4.x)*sg.x,(a.y+b4.y)*sg.y,(a.z+b4.z)*sg.z,(a.w+b4.w)*sg.w);
      int o = q*4; int s = o>>10; int e = o&1023;
      ws[WS_BMT + (e+0)*64 + s] = v.x;
      ws[WS_BMT + (e+1)*64 + s] = v.y;
      ws[WS_BMT + (e+2)*64 + s] = v.z;
      ws[WS_BMT + (e+3)*64 + s] = v.w;
    } else {
      float4 b4 = ((const float4*)bC)[q];
      float4 m4 = ((const float4*)mC)[q];
      float4 sg = sig4_(make_float4(g.x+m4.x, g.y+m4.y, g.z+m4.z, g.w+m4.w));
      float4 v = make_float4((a.x+b4.x)*sg.x,(a.y+b4.y)*sg.y,(a.z+b4.z)*sg.z,(a.w+b4.w)*sg.w);
      int o = q*4; int e = o>>6; int s = o&63;
      ws[WS_CT + (s+0)*1024 + e] = v.x;
      ws[WS_CT + (s+1)*1024 + e] = v.y;
      ws[WS_CT + (s+2)*1024 + e] = v.z;
      ws[WS_CT + (s+3)*1024 + e] = v.w;
    }
  } else if (bb == 128){
    float4 a = {0,0,0,0};
    #pragma unroll
    for (int c=0;c<NCH;c++){
      float4 v = ((const float4*)(ws + WS_PD))[c*256 + tid];
      a.x+=v.x; a.y+=v.y; a.z+=v.z; a.w+=v.w;
    }
    float4 g = {0,0,0,0};
    #pragma unroll
    for (int cg=0;cg<NGCH;cg++){
      float4 v = ((const float4*)(ws + WS_PDG))[cg*256 + tid];
      g.x+=v.x; g.y+=v.y; g.z+=v.z; g.w+=v.w;
    }
    float4 b4 = ((const float4*)bD)[tid];
    float4 m4 = ((const float4*)mD)[tid];
    float4 sg = sig4_(make_float4(g.x+m4.x, g.y+m4.y, g.z+m4.z, g.w+m4.w));
    float4 v = make_float4((a.x+b4.x)*sg.x,(a.y+b4.y)*sg.y,(a.z+b4.z)*sg.z,(a.w+b4.w)*sg.w);
    ((float4*)(ws + WS_D))[tid] = v;
  } else {
    __shared__ float sda[64];
    if (tid < 64){
      int s = tid;
      float A = -softplusf_(ws[WS_PA+s] + bA_[s]) * sigmoidf_(ws[WS_PA+64+s] + mA_[s]);
      float delta = (softplusf_(ws[WS_PDL+s] + bdl[s]) + 1e-4f) * sigmoidf_(ws[WS_PDL+64+s] + mdl[s]);
      float da = delta * A;
      sda[s] = da;
      ws[WS_DELTA+s] = delta;
      ws[WS_ABAR+s]  = expf(da);
      ws[WS_EL+s]    = expf((float)L_*da);
    }
    __syncthreads();
    for (int idx=tid; idx<L_*S_; idx+=256){
      int tl = idx>>6, s = idx&63;
      ws[WS_FAC+idx] = expf((float)(tl+1)*sda[s]);
    }
  }
}

// ---- per-(b,chunk of 32 rows): u = delta ⊙ (x @ Bm^T), zero-state local scan ----
__global__ __launch_bounds__(256) void k_scan(const float* __restrict__ x, float* __restrict__ ws){
  __shared__ float Xs[32][68];     // [trow][k]
  __shared__ float BsT[64][68];    // [k][s]
  __shared__ float Us[32][65];     // [trow][s]
  __shared__ float sdl[S_], sab[S_];
  int tid = threadIdx.x;
  int bb = blockIdx.x;                       // b*NC_ + c
  int row0 = (bb>>7)*T_ + (bb&127)*L_;
  if (tid<64){ sdl[tid]=ws[WS_DELTA+tid]; sab[tid]=ws[WS_ABAR+tid]; }
  float acc[2][4];
  #pragma unroll
  for (int i=0;i<2;i++)
    #pragma unroll
    for (int j=0;j<4;j++) acc[i][j]=0.f;
  int ty = tid>>4, tx = tid&15;
  const float4* x4 = (const float4*)x;
  const float4* BmT4 = (const float4*)(ws + WS_BMT);
  for (int kk=0; kk<EMB_; kk+=64){
    #pragma unroll
    for (int t=0;t<2;t++){
      int fl = t*256+tid; int rr = fl>>4, cq = fl&15;
      float4 xv = x4[(size_t)(row0+rr)*256 + (kk>>2) + cq];
      *(float4*)&Xs[rr][cq*4] = xv;
    }
    #pragma unroll
    for (int t=0;t<4;t++){
      int fl = t*256+tid; int rr = fl>>4, cq = fl&15;
      float4 bv = BmT4[(size_t)(kk+rr)*16 + cq];
      *(float4*)&BsT[rr][cq*4] = bv;
    }
    __syncthreads();
    #pragma unroll 8
    for (int k=0;k<64;k++){
      float4 b4 = *(const float4*)&BsT[k][4*tx];
      float x0 = Xs[2*ty+0][k], x1 = Xs[2*ty+1][k];
      acc[0][0]+=x0*b4.x; acc[0][1]+=x0*b4.y; acc[0][2]+=x0*b4.z; acc[0][3]+=x0*b4.w;
      acc[1][0]+=x1*b4.x; acc[1][1]+=x1*b4.y; acc[1][2]+=x1*b4.z; acc[1][3]+=x1*b4.w;
    }
    __syncthreads();
  }
  #pragma unroll
  for (int i=0;i<2;i++)
    #pragma unroll
    for (int j=0;j<4;j++)
      Us[2*ty+i][4*tx+j] = acc[i][j]*sdl[4*tx+j];
  __syncthreads();
  if (tid<64){
    int s = tid; float h = 0.f, ab = sab[s];
    #pragma unroll 8
    for (int t=0;t<L_;t++){
      h = fmaf(ab, h, Us[t][s]);
      ws[WS_HLOC + (row0+t)*S_ + s] = h;
    }
    ws[WS_CHEND + bb*S_ + s] = h;
  }
}

// ---- chain chunk boundary states ----
__global__ void k_carry(float* __restrict__ ws){
  int tid = threadIdx.x;                     // 256 = (b,s)
  int b = tid>>6, s = tid&63;
  float el = ws[WS_EL + s];
  float carry = 0.f;
  #pragma unroll 8
  for (int c=0;c<NC_;c++){
    int idx = (b*NC_ + c)*S_ + s;
    ws[WS_CARRY + idx] = carry;
    carry = fmaf(el, carry, ws[WS_CHEND + idx]);
  }
}

// ---- out = (hloc + fac*carry) @ C^T + D*x ----
__global__ __launch_bounds__(256) void k_out(const float* __restrict__ x,
                                             const float* __restrict__ ws,
                                             float* __restrict__ out){
  __shared__ float Cts[64][68];    // [s][elocal]
  __shared__ float Hs[64][68];     // [trow][s]
  int tid = threadIdx.x;
  int bb = blockIdx.x;
  int rt = bb & 255, et = bb >> 8;           // 256 row tiles x 16 e-tiles
  int row0 = rt*64, e0 = et*64;
  int b = row0 >> 12;
  int cbase = b*NC_ + ((row0 & (T_-1)) >> 5);
  const float4* hl4 = (const float4*)(ws + WS_HLOC);
  const float4* fc4 = (const float4*)(ws + WS_FAC);
  const float4* cr4 = (const float4*)(ws + WS_CARRY);
  const float4* CT4 = (const float4*)(ws + WS_CT);
  #pragma unroll
  for (int t=0;t<4;t++){
    int fl = t*256+tid; int rr = fl>>4, q = fl&15;
    float4 h = hl4[(size_t)(row0+rr)*16 + q];
    float4 f = fc4[(rr & (L_-1))*16 + q];
    float4 c = cr4[(cbase + (rr>>5))*16 + q];
    float4 hv = make_float4(h.x+f.x*c.x, h.y+f.y*c.y, h.z+f.z*c.z, h.w+f.w*c.w);
    *(float4*)&Hs[rr][q*4] = hv;
    float4 ct = CT4[(size_t)rr*256 + (e0>>2) + q];
    *(float4*)&Cts[rr][q*4] = ct;
  }
  __syncthreads();
  int ty = tid>>4, tx = tid&15;
  float acc[4][4];
  #pragma unroll
  for (int i=0;i<4;i++)
    #pragma unroll
    for (int j=0;j<4;j++) acc[i][j]=0.f;
  #pragma unroll 8
  for (int s=0;s<64;s++){
    float4 c4 = *(const float4*)&Cts[s][4*tx];
    float h0 = Hs[4*ty+0][s], h1 = Hs[4*ty+1][s], h2 = Hs[4*ty+2][s], h3 = Hs[4*ty+3][s];
    acc[0][0]+=h0*c4.x; acc[0][1]+=h0*c4.y; acc[0][2]+=h0*c4.z; acc[0][3]+=h0*c4.w;
    acc[1][0]+=h1*c4.x; acc[1][1]+=h1*c4.y; acc[1][2]+=h1*c4.z; acc[1][3]+=h1*c4.w;
    acc[2][0]+=h2*c4.x; acc[2][1]+=h2*c4.y; acc[2][2]+=h2*c4.z; acc[2][3]+=h2*c4.w;
    acc[3][0]+=h3*c4.x; acc[3][1]+=h3*c4.y; acc[3][2]+=h3*c4.z; acc[3][3]+=h3*c4.w;
  }
  float4 d4 = ((const float4*)(ws + WS_D))[(e0>>2) + tx];
  #pragma unroll
  for (int i=0;i<4;i++){
    int row = row0 + 4*ty + i;
    float4 x4v = reinterpret_cast<const float4*>(x + (size_t)row*EMB_ + e0)[tx];
    float4 o;
    o.x = acc[i][0] + d4.x*x4v.x;
    o.y = acc[i][1] + d4.y*x4v.y;
    o.z = acc[i][2] + d4.z*x4v.z;
    o.w = acc[i][3] + d4.w*x4v.w;
    reinterpret_cast<float4*>(out + (size_t)row*EMB_ + e0)[tx] = o;
  }
}

extern "C" void kernel_launch(void* const* d_in, const int* in_sizes, int n_in,
                              void* d_out, int out_size, void* d_ws, size_t ws_size,
                              hipStream_t stream){
  const float* te  = (const float*)d_in[0];
  const float* x   = (const float*)d_in[1];
  const float* W1  = (const float*)d_in[2];
  const float* b1  = (const float*)d_in[3];
  const float* W2  = (const float*)d_in[4];
  const float* b2  = (const float*)d_in[5];
  const float* WA  = (const float*)d_in[6];
  const float* bA  = (const float*)d_in[7];
  const float* WB  = (const float*)d_in[8];
  const float* bB  = (const float*)d_in[9];
  const float* WC  = (const float*)d_in[10];
  const float* bC  = (const float*)d_in[11];
  const float* WD  = (const float*)d_in[12];
  const float* bD  = (const float*)d_in[13];
  const float* Wdl = (const float*)d_in[14];
  const float* bdl = (const float*)d_in[15];
  const float* MA  = (const float*)d_in[16];
  const float* mA  = (const float*)d_in[17];
  const float* MB  = (const float*)d_in[18];
  const float* mB  = (const float*)d_in[19];
  const float* MC  = (const float*)d_in[20];
  const float* mC  = (const float*)d_in[21];
  const float* MD  = (const float*)d_in[22];
  const float* mD  = (const float*)d_in[23];
  const float* Mdl = (const float*)d_in[24];
  const float* mdl = (const float*)d_in[25];
  float* ws  = (float*)d_ws;
  float* out = (float*)d_out;

  k_t1<<<8,64,0,stream>>>(te, W1, b1, ws);
  k_t2<<<8,512,0,stream>>>(W2, b2, ws);
  k_partial<<<1302,256,0,stream>>>(te, WB,MB, WC,MC, WD,MD, WA,MA, Wdl,Mdl, ws);
  k_finalize<<<130,256,0,stream>>>(bB,mB, bC,mC, bD,mD, bA,mA, bdl,mdl, ws);
  k_scan<<<512,256,0,stream>>>(x, ws);
  k_carry<<<1,256,0,stream>>>(ws);
  k_out<<<4096,256,0,stream>>>(x, ws, out);
}

// Round 6
// 186.972 us; speedup vs baseline: 1.0352x; 1.0352x over previous
//
#include <hip/hip_runtime.h>
#include <math.h>

#define SIN_ 128
#define TEMB_ 512
#define EMB_ 1024
#define S_ 64
#define B_ 4
#define T_ 4096
#define NROW (B_*T_)          // 16384
#define L_ 32                 // scan chunk length
#define NC_ (T_/L_)           // 128 chunks per batch row

#define GK 32                 // K-rows per partial block
#define NSL 16                // column slices per region (slice = 4096 floats = 16 KB)
#define NCH 16                // W chunks (512/GK)
#define NGCH 4                // gate chunks (128/GK)

// workspace layout (float offsets)
#define WS_T1     0
#define WS_T2     512
#define WS_DELTA  1024
#define WS_ABAR   1088
#define WS_EL     1152
#define WS_FAC    1216                    // L_*S_ = 2048
#define WS_D      3264                    // 1024
#define WS_BMTH   4288                    // bf16 BmT[e][s]: 65536 ushorts = 32768 slots
#define WS_CTH    37056                   // bf16 CT[s][e]:  65536 ushorts = 32768 slots
#define WS_PD     69824                   // 16*1024 f32
#define WS_PDG    86208                   // 4*1024 f32
#define WS_PA     90304                   // A sums [64] + gate [64]
#define WS_PDL    90432                   // dl sums [64] + gate [64]
#define WS_PBF    90560                   // bf16 partials: 2,621,440 ushorts = 1,310,720 slots
// W partials: ushort4 idx 0      .. 524288   ([2][16][16][1024])
// G partials: ushort4 idx 524288 .. 655360   ([2][16][4][1024])
#define WS_HLOCH  90560                   // overlay on PBF: bf16 hloc[NROW][S] (524288 slots)
#define WS_CHEND  1401280                 // 32768 f32
#define WS_CARRY  1434048                 // 32768 f32
// total 1,466,816 floats = 5.87 MB

__device__ __forceinline__ float sigmoidf_(float x){ return 1.f/(1.f+expf(-x)); }
__device__ __forceinline__ float softplusf_(float x){ return x>20.f ? x : log1pf(expf(x)); }
__device__ __forceinline__ float4 sig4_(float4 g){
  float4 r; r.x=sigmoidf_(g.x); r.y=sigmoidf_(g.y); r.z=sigmoidf_(g.z); r.w=sigmoidf_(g.w); return r;
}
__device__ __forceinline__ unsigned short f2bf(float x){
  unsigned int u = __float_as_uint(x);
  unsigned int r = (u + 0x7FFFu + ((u>>16)&1u)) >> 16;
  return (unsigned short)r;
}
__device__ __forceinline__ ushort4 pack4(float4 v){
  return make_ushort4(f2bf(v.x),f2bf(v.y),f2bf(v.z),f2bf(v.w));
}
__device__ __forceinline__ float bf2f(unsigned short h){
  return __uint_as_float(((unsigned int)h)<<16);
}

// ---- t1 = silu(te @ W1 + b1) ----
__global__ void k_t1(const float* __restrict__ te, const float* __restrict__ W1,
                     const float* __restrict__ b1, float* __restrict__ ws){
  __shared__ float ste[SIN_];
  int tid = threadIdx.x;                 // 64 threads, 8 blocks
  ste[tid] = te[tid]; ste[tid+64] = te[tid+64];
  __syncthreads();
  int j = blockIdx.x*64 + tid;
  float a = b1[j];
  #pragma unroll 16
  for (int i=0;i<SIN_;i++) a += ste[i]*W1[i*TEMB_ + j];
  ws[WS_T1 + j] = a * sigmoidf_(a);
}

// ---- t2 = t1 @ W2 + b2 ----
__global__ __launch_bounds__(512) void k_t2(const float* __restrict__ W2,
                                            const float* __restrict__ b2,
                                            float* __restrict__ ws){
  __shared__ float st1[TEMB_];
  __shared__ float red[8][64];
  int tid = threadIdx.x;
  st1[tid] = ws[WS_T1 + tid];
  __syncthreads();
  int jl = tid & 63, kc = tid >> 6;
  int j = blockIdx.x*64 + jl;
  float p = 0.f;
  #pragma unroll 8
  for (int i=0;i<64;i++){
    int k = kc*64 + i;
    p += st1[k]*W2[k*TEMB_ + j];
  }
  red[kc][jl] = p;
  __syncthreads();
  if (tid < 64){
    float a = b2[blockIdx.x*64 + tid];
    #pragma unroll
    for (int c=0;c<8;c++) a += red[c][tid];
    ws[WS_T2 + blockIdx.x*64 + tid] = a;
  }
}

// ---- split-K partial sums, wide contiguous chunks (R4 structure: at read-cap) ----
__global__ __launch_bounds__(256,2) void k_partial(
    const float* __restrict__ te,
    const float* __restrict__ WB, const float* __restrict__ MB,
    const float* __restrict__ WC, const float* __restrict__ MC,
    const float* __restrict__ WD, const float* __restrict__ MD,
    const float* __restrict__ WA, const float* __restrict__ MA,
    const float* __restrict__ Wdl, const float* __restrict__ Mdl,
    float* __restrict__ ws){
  __shared__ float st2[TEMB_];
  __shared__ float ste[SIN_];
  int tid = threadIdx.x;
  st2[tid] = ws[WS_T2 + tid];
  st2[tid+256] = ws[WS_T2 + tid + 256];
  if (tid < SIN_) ste[tid] = te[tid];
  __syncthreads();
  unsigned short* pbf = (unsigned short*)(ws + WS_PBF);
  int bb = blockIdx.x;
  if (bb < 512){
    int r = bb>>8, rem = bb&255, j = rem>>4, c = rem&15;
    const float4* W4 = (const float4*)(r ? WC : WB);
    const float4* base = W4 + (size_t)(c*GK)*16384 + j*1024 + tid;
    const float* coef = st2 + c*GK;
    float4 a0={0,0,0,0}, a1={0,0,0,0}, a2={0,0,0,0}, a3={0,0,0,0};
    #pragma unroll 4
    for (int k=0;k<GK;k++){
      const float4* p = base + (size_t)k*16384;
      float4 w0=p[0], w1=p[256], w2=p[512], w3=p[768];
      float cv = coef[k];
      a0.x=fmaf(cv,w0.x,a0.x); a0.y=fmaf(cv,w0.y,a0.y); a0.z=fmaf(cv,w0.z,a0.z); a0.w=fmaf(cv,w0.w,a0.w);
      a1.x=fmaf(cv,w1.x,a1.x); a1.y=fmaf(cv,w1.y,a1.y); a1.z=fmaf(cv,w1.z,a1.z); a1.w=fmaf(cv,w1.w,a1.w);
      a2.x=fmaf(cv,w2.x,a2.x); a2.y=fmaf(cv,w2.y,a2.y); a2.z=fmaf(cv,w2.z,a2.z); a2.w=fmaf(cv,w2.w,a2.w);
      a3.x=fmaf(cv,w3.x,a3.x); a3.y=fmaf(cv,w3.y,a3.y); a3.z=fmaf(cv,w3.z,a3.z); a3.w=fmaf(cv,w3.w,a3.w);
    }
    ushort4* dst = (ushort4*)pbf + (size_t)((r*NSL+j)*NCH + c)*1024;
    dst[tid]     = pack4(a0);
    dst[tid+256] = pack4(a1);
    dst[tid+512] = pack4(a2);
    dst[tid+768] = pack4(a3);
  } else if (bb < 640){
    int g = bb-512, r = g>>6, rem = g&63, j = rem>>2, cg = rem&3;
    const float4* M4 = (const float4*)(r ? MC : MB);
    const float4* base = M4 + (size_t)(cg*GK)*16384 + j*1024 + tid;
    const float* coef = ste + cg*GK;
    float4 a0={0,0,0,0}, a1={0,0,0,0}, a2={0,0,0,0}, a3={0,0,0,0};
    #pragma unroll 4
    for (int k=0;k<GK;k++){
      const float4* p = base + (size_t)k*16384;
      float4 w0=p[0], w1=p[256], w2=p[512], w3=p[768];
      float cv = coef[k];
      a0.x=fmaf(cv,w0.x,a0.x); a0.y=fmaf(cv,w0.y,a0.y); a0.z=fmaf(cv,w0.z,a0.z); a0.w=fmaf(cv,w0.w,a0.w);
      a1.x=fmaf(cv,w1.x,a1.x); a1.y=fmaf(cv,w1.y,a1.y); a1.z=fmaf(cv,w1.z,a1.z); a1.w=fmaf(cv,w1.w,a1.w);
      a2.x=fmaf(cv,w2.x,a2.x); a2.y=fmaf(cv,w2.y,a2.y); a2.z=fmaf(cv,w2.z,a2.z); a2.w=fmaf(cv,w2.w,a2.w);
      a3.x=fmaf(cv,w3.x,a3.x); a3.y=fmaf(cv,w3.y,a3.y); a3.z=fmaf(cv,w3.z,a3.z); a3.w=fmaf(cv,w3.w,a3.w);
    }
    ushort4* dst = (ushort4*)pbf + (size_t)524288 + (size_t)((r*NSL+j)*NGCH + cg)*1024;
    dst[tid]     = pack4(a0);
    dst[tid+256] = pack4(a1);
    dst[tid+512] = pack4(a2);
    dst[tid+768] = pack4(a3);
  } else if (bb < 656){
    int c = bb-640;
    const float4* base = (const float4*)WD + (size_t)(c*GK)*256 + tid;
    const float* coef = st2 + c*GK;
    float4 a={0,0,0,0};
    #pragma unroll 4
    for (int k=0;k<GK;k++){
      float4 w = base[(size_t)k*256];
      float cv = coef[k];
      a.x=fmaf(cv,w.x,a.x); a.y=fmaf(cv,w.y,a.y); a.z=fmaf(cv,w.z,a.z); a.w=fmaf(cv,w.w,a.w);
    }
    ((float4*)(ws + WS_PD))[c*256 + tid] = a;
  } else if (bb < 660){
    int cg = bb-656;
    const float4* base = (const float4*)MD + (size_t)(cg*GK)*256 + tid;
    const float* coef = ste + cg*GK;
    float4 a={0,0,0,0};
    #pragma unroll 4
    for (int k=0;k<GK;k++){
      float4 w = base[(size_t)k*256];
      float cv = coef[k];
      a.x=fmaf(cv,w.x,a.x); a.y=fmaf(cv,w.y,a.y); a.z=fmaf(cv,w.z,a.z); a.w=fmaf(cv,w.w,a.w);
    }
    ((float4*)(ws + WS_PDG))[cg*256 + tid] = a;
  } else {
    const float* Wm = (bb==660) ? WA : Wdl;
    const float* Mm = (bb==660) ? MA : Mdl;
    int outbase = (bb==660) ? WS_PA : WS_PDL;
    __shared__ float red[16][68];
    int q = tid&15, kr = tid>>4;
    float4 acc={0,0,0,0};
    const float4* W4 = (const float4*)Wm;
    #pragma unroll 4
    for (int it=0; it<32; ++it){
      int k = it*16 + kr;
      float4 w = W4[k*16 + q];
      float cv = st2[k];
      acc.x=fmaf(cv,w.x,acc.x); acc.y=fmaf(cv,w.y,acc.y); acc.z=fmaf(cv,w.z,acc.z); acc.w=fmaf(cv,w.w,acc.w);
    }
    red[kr][4*q+0]=acc.x; red[kr][4*q+1]=acc.y; red[kr][4*q+2]=acc.z; red[kr][4*q+3]=acc.w;
    __syncthreads();
    if (tid < 64){
      float s = 0.f;
      #pragma unroll
      for (int g=0;g<16;g++) s += red[g][tid];
      ws[outbase + tid] = s;
    }
    __syncthreads();
    float4 gac={0,0,0,0};
    const float4* M4 = (const float4*)Mm;
    #pragma unroll 4
    for (int it=0; it<8; ++it){
      int k = it*16 + kr;
      float4 w = M4[k*16 + q];
      float cv = ste[k];
      gac.x=fmaf(cv,w.x,gac.x); gac.y=fmaf(cv,w.y,gac.y); gac.z=fmaf(cv,w.z,gac.z); gac.w=fmaf(cv,w.w,gac.w);
    }
    red[kr][4*q+0]=gac.x; red[kr][4*q+1]=gac.y; red[kr][4*q+2]=gac.z; red[kr][4*q+3]=gac.w;
    __syncthreads();
    if (tid < 64){
      float s = 0.f;
      #pragma unroll
      for (int g=0;g<16;g++) s += red[g][tid];
      ws[outbase + 64 + tid] = s;
    }
  }
}

// ---- finalize: reduce bf16 partials, bias+gate, write bf16 BmT/CT + f32 D; A/delta/fac ----
__global__ __launch_bounds__(256) void k_finalize(
    const float* __restrict__ bB, const float* __restrict__ mB,
    const float* __restrict__ bC, const float* __restrict__ mC,
    const float* __restrict__ bD, const float* __restrict__ mD,
    const float* __restrict__ bA_, const float* __restrict__ mA_,
    const float* __restrict__ bdl, const float* __restrict__ mdl,
    float* __restrict__ ws){
  int tid = threadIdx.x, bb = blockIdx.x;
  const ushort4* pbf4 = (const ushort4*)(ws + WS_PBF);
  unsigned short* bmth = (unsigned short*)(ws + WS_BMTH);
  unsigned short* cth  = (unsigned short*)(ws + WS_CTH);
  if (bb < 128){
    int r = bb>>6;
    int q = (bb&63)*256 + tid;        // f4 idx within region [0,16384)
    int j = q>>10, p = q&1023;
    float4 a = {0,0,0,0};
    size_t wbase = ((size_t)(r*NSL+j)*NCH)*1024 + p;
    #pragma unroll
    for (int c=0;c<NCH;c++){
      ushort4 v = pbf4[wbase + (size_t)c*1024];
      a.x += bf2f(v.x); a.y += bf2f(v.y); a.z += bf2f(v.z); a.w += bf2f(v.w);
    }
    float4 g = {0,0,0,0};
    size_t gbase = (size_t)524288 + ((size_t)(r*NSL+j)*NGCH)*1024 + p;
    #pragma unroll
    for (int cg=0;cg<NGCH;cg++){
      ushort4 v = pbf4[gbase + (size_t)cg*1024];
      g.x += bf2f(v.x); g.y += bf2f(v.y); g.z += bf2f(v.z); g.w += bf2f(v.w);
    }
    if (r == 0){
      float4 b4 = ((const float4*)bB)[q];
      float4 m4 = ((const float4*)mB)[q];
      float4 sg = sig4_(make_float4(g.x+m4.x, g.y+m4.y, g.z+m4.z, g.w+m4.w));
      float4 v = make_float4((a.x+b4.x)*sg.x,(a.y+b4.y)*sg.y,(a.z+b4.z)*sg.z,(a.w+b4.w)*sg.w);
      int o = q*4; int s = o>>10; int e = o&1023;
      bmth[(e+0)*64 + s] = f2bf(v.x);
      bmth[(e+1)*64 + s] = f2bf(v.y);
      bmth[(e+2)*64 + s] = f2bf(v.z);
      bmth[(e+3)*64 + s] = f2bf(v.w);
    } else {
      float4 b4 = ((const float4*)bC)[q];
      float4 m4 = ((const float4*)mC)[q];
      float4 sg = sig4_(make_float4(g.x+m4.x, g.y+m4.y, g.z+m4.z, g.w+m4.w));
      float4 v = make_float4((a.x+b4.x)*sg.x,(a.y+b4.y)*sg.y,(a.z+b4.z)*sg.z,(a.w+b4.w)*sg.w);
      int o = q*4; int e = o>>6; int s = o&63;
      cth[(s+0)*1024 + e] = f2bf(v.x);
      cth[(s+1)*1024 + e] = f2bf(v.y);
      cth[(s+2)*1024 + e] = f2bf(v.z);
      cth[(s+3)*1024 + e] = f2bf(v.w);
    }
  } else if (bb == 128){
    float4 a = {0,0,0,0};
    #pragma unroll
    for (int c=0;c<NCH;c++){
      float4 v = ((const float4*)(ws + WS_PD))[c*256 + tid];
      a.x+=v.x; a.y+=v.y; a.z+=v.z; a.w+=v.w;
    }
    float4 g = {0,0,0,0};
    #pragma unroll
    for (int cg=0;cg<NGCH;cg++){
      float4 v = ((const float4*)(ws + WS_PDG))[cg*256 + tid];
      g.x+=v.x; g.y+=v.y; g.z+=v.z; g.w+=v.w;
    }
    float4 b4 = ((const float4*)bD)[tid];
    float4 m4 = ((const float4*)mD)[tid];
    float4 sg = sig4_(make_float4(g.x+m4.x, g.y+m4.y, g.z+m4.z, g.w+m4.w));
    float4 v = make_float4((a.x+b4.x)*sg.x,(a.y+b4.y)*sg.y,(a.z+b4.z)*sg.z,(a.w+b4.w)*sg.w);
    ((float4*)(ws + WS_D))[tid] = v;
  } else {
    __shared__ float sda[64];
    if (tid < 64){
      int s = tid;
      float A = -softplusf_(ws[WS_PA+s] + bA_[s]) * sigmoidf_(ws[WS_PA+64+s] + mA_[s]);
      float delta = (softplusf_(ws[WS_PDL+s] + bdl[s]) + 1e-4f) * sigmoidf_(ws[WS_PDL+64+s] + mdl[s]);
      float da = delta * A;
      sda[s] = da;
      ws[WS_DELTA+s] = delta;
      ws[WS_ABAR+s]  = expf(da);
      ws[WS_EL+s]    = expf((float)L_*da);
    }
    __syncthreads();
    for (int idx=tid; idx<L_*S_; idx+=256){
      int tl = idx>>6, s = idx&63;
      ws[WS_FAC+idx] = expf((float)(tl+1)*sda[s]);
    }
  }
}

// ---- per-(b,chunk of 32 rows): u = delta ⊙ (x @ Bm^T), zero-state local scan ----
__global__ __launch_bounds__(256) void k_scan(const float* __restrict__ x, float* __restrict__ ws){
  __shared__ float Xs[32][68];     // [trow][k]
  __shared__ float BsT[64][68];    // [k][s]
  __shared__ float Us[32][65];     // [trow][s]
  __shared__ float sdl[S_], sab[S_];
  int tid = threadIdx.x;
  int bb = blockIdx.x;                       // b*NC_ + c
  int row0 = (bb>>7)*T_ + (bb&127)*L_;
  if (tid<64){ sdl[tid]=ws[WS_DELTA+tid]; sab[tid]=ws[WS_ABAR+tid]; }
  float acc[2][4];
  #pragma unroll
  for (int i=0;i<2;i++)
    #pragma unroll
    for (int j=0;j<4;j++) acc[i][j]=0.f;
  int ty = tid>>4, tx = tid&15;
  const float4* x4 = (const float4*)x;
  const ushort4* bm4 = (const ushort4*)(ws + WS_BMTH);
  for (int kk=0; kk<EMB_; kk+=64){
    #pragma unroll
    for (int t=0;t<2;t++){
      int fl = t*256+tid; int rr = fl>>4, cq = fl&15;
      float4 xv = x4[(size_t)(row0+rr)*256 + (kk>>2) + cq];
      *(float4*)&Xs[rr][cq*4] = xv;
    }
    #pragma unroll
    for (int t=0;t<4;t++){
      int fl = t*256+tid; int rr = fl>>4, cq = fl&15;
      ushort4 hv = bm4[(size_t)(kk+rr)*16 + cq];
      *(float4*)&BsT[rr][cq*4] = make_float4(bf2f(hv.x),bf2f(hv.y),bf2f(hv.z),bf2f(hv.w));
    }
    __syncthreads();
    #pragma unroll 8
    for (int k=0;k<64;k++){
      float4 b4 = *(const float4*)&BsT[k][4*tx];
      float x0 = Xs[2*ty+0][k], x1 = Xs[2*ty+1][k];
      acc[0][0]+=x0*b4.x; acc[0][1]+=x0*b4.y; acc[0][2]+=x0*b4.z; acc[0][3]+=x0*b4.w;
      acc[1][0]+=x1*b4.x; acc[1][1]+=x1*b4.y; acc[1][2]+=x1*b4.z; acc[1][3]+=x1*b4.w;
    }
    __syncthreads();
  }
  #pragma unroll
  for (int i=0;i<2;i++)
    #pragma unroll
    for (int j=0;j<4;j++)
      Us[2*ty+i][4*tx+j] = acc[i][j]*sdl[4*tx+j];
  __syncthreads();
  if (tid<64){
    unsigned short* hh = (unsigned short*)(ws + WS_HLOCH);
    int s = tid; float h = 0.f, ab = sab[s];
    #pragma unroll 8
    for (int t=0;t<L_;t++){
      h = fmaf(ab, h, Us[t][s]);
      hh[(size_t)(row0+t)*S_ + s] = f2bf(h);
    }
    ws[WS_CHEND + bb*S_ + s] = h;
  }
}

// ---- chain chunk boundary states: LDS-staged (kills the dependent-global-latency chain) ----
__global__ __launch_bounds__(256) void k_carry(float* __restrict__ ws){
  __shared__ float ch[B_*NC_*S_];            // 32768 f = 128 KB
  int tid = threadIdx.x;
  const float4* src = (const float4*)(ws + WS_CHEND);
  float4* chv = (float4*)ch;
  for (int i=tid;i<8192;i+=256) chv[i] = src[i];
  __syncthreads();
  int b = tid>>6, s = tid&63;
  float el = ws[WS_EL + s];
  float carry = 0.f;
  #pragma unroll 8
  for (int c=0;c<NC_;c++){
    int idx = (b*NC_ + c)*S_ + s;
    float v = ch[idx];
    ch[idx] = carry;                         // in-place: becomes CARRY
    carry = fmaf(el, carry, v);
  }
  __syncthreads();
  float4* dst = (float4*)(ws + WS_CARRY);
  for (int i=tid;i<8192;i+=256) dst[i] = chv[i];
}

// ---- out = (hloc + fac*carry) @ C^T + D*x ----
__global__ __launch_bounds__(256) void k_out(const float* __restrict__ x,
                                             const float* __restrict__ ws,
                                             float* __restrict__ out){
  __shared__ float Cts[64][68];    // [s][elocal]
  __shared__ float Hs[64][68];     // [trow][s]
  int tid = threadIdx.x;
  int bb = blockIdx.x;
  int rt = bb & 255, et = bb >> 8;           // 256 row tiles x 16 e-tiles
  int row0 = rt*64, e0 = et*64;
  int b = row0 >> 12;
  int cbase = b*NC_ + ((row0 & (T_-1)) >> 5);
  const ushort4* hl4h = (const ushort4*)(ws + WS_HLOCH);
  const ushort4* cth4 = (const ushort4*)(ws + WS_CTH);
  const float4* fc4 = (const float4*)(ws + WS_FAC);
  const float4* cr4 = (const float4*)(ws + WS_CARRY);
  #pragma unroll
  for (int t=0;t<4;t++){
    int fl = t*256+tid; int rr = fl>>4, q = fl&15;
    ushort4 h4 = hl4h[(size_t)(row0+rr)*16 + q];
    float4 f = fc4[(rr & (L_-1))*16 + q];
    float4 c = cr4[(cbase + (rr>>5))*16 + q];
    float4 hv = make_float4(bf2f(h4.x)+f.x*c.x, bf2f(h4.y)+f.y*c.y,
                            bf2f(h4.z)+f.z*c.z, bf2f(h4.w)+f.w*c.w);
    *(float4*)&Hs[rr][q*4] = hv;
    ushort4 ct4 = cth4[(size_t)rr*256 + (e0>>2) + q];
    *(float4*)&Cts[rr][q*4] = make_float4(bf2f(ct4.x),bf2f(ct4.y),bf2f(ct4.z),bf2f(ct4.w));
  }
  __syncthreads();
  int ty = tid>>4, tx = tid&15;
  float acc[4][4];
  #pragma unroll
  for (int i=0;i<4;i++)
    #pragma unroll
    for (int j=0;j<4;j++) acc[i][j]=0.f;
  #pragma unroll 8
  for (int s=0;s<64;s++){
    float4 c4 = *(const float4*)&Cts[s][4*tx];
    float h0 = Hs[4*ty+0][s], h1 = Hs[4*ty+1][s], h2 = Hs[4*ty+2][s], h3 = Hs[4*ty+3][s];
    acc[0][0]+=h0*c4.x; acc[0][1]+=h0*c4.y; acc[0][2]+=h0*c4.z; acc[0][3]+=h0*c4.w;
    acc[1][0]+=h1*c4.x; acc[1][1]+=h1*c4.y; acc[1][2]+=h1*c4.z; acc[1][3]+=h1*c4.w;
    acc[2][0]+=h2*c4.x; acc[2][1]+=h2*c4.y; acc[2][2]+=h2*c4.z; acc[2][3]+=h2*c4.w;
    acc[3][0]+=h3*c4.x; acc[3][1]+=h3*c4.y; acc[3][2]+=h3*c4.z; acc[3][3]+=h3*c4.w;
  }
  float4 d4 = ((const float4*)(ws + WS_D))[(e0>>2) + tx];
  #pragma unroll
  for (int i=0;i<4;i++){
    int row = row0 + 4*ty + i;
    float4 x4v = reinterpret_cast<const float4*>(x + (size_t)row*EMB_ + e0)[tx];
    float4 o;
    o.x = acc[i][0] + d4.x*x4v.x;
    o.y = acc[i][1] + d4.y*x4v.y;
    o.z = acc[i][2] + d4.z*x4v.z;
    o.w = acc[i][3] + d4.w*x4v.w;
    reinterpret_cast<float4*>(out + (size_t)row*EMB_ + e0)[tx] = o;
  }
}

extern "C" void kernel_launch(void* const* d_in, const int* in_sizes, int n_in,
                              void* d_out, int out_size, void* d_ws, size_t ws_size,
                              hipStream_t stream){
  const float* te  = (const float*)d_in[0];
  const float* x   = (const float*)d_in[1];
  const float* W1  = (const float*)d_in[2];
  const float* b1  = (const float*)d_in[3];
  const float* W2  = (const float*)d_in[4];
  const float* b2  = (const float*)d_in[5];
  const float* WA  = (const float*)d_in[6];
  const float* bA  = (const float*)d_in[7];
  const float* WB  = (const float*)d_in[8];
  const float* bB  = (const float*)d_in[9];
  const float* WC  = (const float*)d_in[10];
  const float* bC  = (const float*)d_in[11];
  const float* WD  = (const float*)d_in[12];
  const float* bD  = (const float*)d_in[13];
  const float* Wdl = (const float*)d_in[14];
  const float* bdl = (const float*)d_in[15];
  const float* MA  = (const float*)d_in[16];
  const float* mA  = (const float*)d_in[17];
  const float* MB  = (const float*)d_in[18];
  const float* mB  = (const float*)d_in[19];
  const float* MC  = (const float*)d_in[20];
  const float* mC  = (const float*)d_in[21];
  const float* MD  = (const float*)d_in[22];
  const float* mD  = (const float*)d_in[23];
  const float* Mdl = (const float*)d_in[24];
  const float* mdl = (const float*)d_in[25];
  float* ws  = (float*)d_ws;
  float* out = (float*)d_out;

  k_t1<<<8,64,0,stream>>>(te, W1, b1, ws);
  k_t2<<<8,512,0,stream>>>(W2, b2, ws);
  k_partial<<<662,256,0,stream>>>(te, WB,MB, WC,MC, WD,MD, WA,MA, Wdl,Mdl, ws);
  k_finalize<<<130,256,0,stream>>>(bB,mB, bC,mC, bD,mD, bA,mA, bdl,mdl, ws);
  k_scan<<<512,256,0,stream>>>(x, ws);
  k_carry<<<1,256,0,stream>>>(ws);
  k_out<<<4096,256,0,stream>>>(x, ws, out);
}

// Round 8
// 159.625 us; speedup vs baseline: 1.2125x; 1.1713x over previous
//
#include <hip/hip_runtime.h>
#include <math.h>

#define SIN_ 128
#define TEMB_ 512
#define EMB_ 1024
#define S_ 64
#define B_ 4
#define T_ 4096
#define NROW (B_*T_)          // 16384
#define L_ 64                 // scan chunk length
#define NC_ (T_/L_)           // 64 chunks per batch row

#define GK 32                 // K-rows per partial block
#define NSL 16                // column slices per region (slice = 4096 floats = 16 KB)
#define NCH 16                // W chunks (512/GK)
#define NGCH 4                // gate chunks (128/GK)

// workspace layout (float offsets)
#define WS_T1     0
#define WS_T2     512
#define WS_DELTA  1024
#define WS_ABAR   1088
#define WS_EL     1152
#define WS_FAC    1216                    // L_*S_ = 4096
#define WS_D      5312                    // 1024
#define WS_BMTH   6336                    // bf16 BmT[e][s]: 65536 ushorts = 32768 slots
#define WS_CTH    39104                   // bf16 CT[s][e]:  65536 ushorts = 32768 slots
#define WS_PD     71872                   // 16*1024 f32
#define WS_PDG    88256                   // 4*1024 f32
#define WS_PA     92352                   // A sums [64] + gate [64]
#define WS_PDL    92480                   // dl sums [64] + gate [64]
#define WS_PBF    92608                   // bf16 partials: 2,621,440 ushorts = 1,310,720 slots
#define WS_HLOCH  92608                   // overlay on PBF: bf16 hloc[NROW][S] (524288 slots)
#define WS_CHEND  1403328                 // B_*NC_*S_ = 16384 f32
#define WS_CARRY  1419712                 // 16384 f32
// total 1,436,096 floats = 5.74 MB

typedef float nt4 __attribute__((ext_vector_type(4)));

__device__ __forceinline__ float sigmoidf_(float x){ return 1.f/(1.f+expf(-x)); }
__device__ __forceinline__ float softplusf_(float x){ return x>20.f ? x : log1pf(expf(x)); }
__device__ __forceinline__ float4 sig4_(float4 g){
  float4 r; r.x=sigmoidf_(g.x); r.y=sigmoidf_(g.y); r.z=sigmoidf_(g.z); r.w=sigmoidf_(g.w); return r;
}
__device__ __forceinline__ unsigned short f2bf(float x){
  unsigned int u = __float_as_uint(x);
  unsigned int r = (u + 0x7FFFu + ((u>>16)&1u)) >> 16;
  return (unsigned short)r;
}
__device__ __forceinline__ ushort4 pack4nt(nt4 v){
  return make_ushort4(f2bf(v.x),f2bf(v.y),f2bf(v.z),f2bf(v.w));
}
__device__ __forceinline__ float bf2f(unsigned short h){
  return __uint_as_float(((unsigned int)h)<<16);
}
__device__ __forceinline__ nt4 ntload(const float4* p){
  return __builtin_nontemporal_load((const nt4*)p);
}

// ---- t1 = silu(te @ W1 + b1) ----
__global__ void k_t1(const float* __restrict__ te, const float* __restrict__ W1,
                     const float* __restrict__ b1, float* __restrict__ ws){
  __shared__ float ste[SIN_];
  int tid = threadIdx.x;                 // 64 threads, 8 blocks
  ste[tid] = te[tid]; ste[tid+64] = te[tid+64];
  __syncthreads();
  int j = blockIdx.x*64 + tid;
  float a = b1[j];
  #pragma unroll 16
  for (int i=0;i<SIN_;i++) a += ste[i]*W1[i*TEMB_ + j];
  ws[WS_T1 + j] = a * sigmoidf_(a);
}

// ---- t2 = t1 @ W2 + b2 ----
__global__ __launch_bounds__(512) void k_t2(const float* __restrict__ W2,
                                            const float* __restrict__ b2,
                                            float* __restrict__ ws){
  __shared__ float st1[TEMB_];
  __shared__ float red[8][64];
  int tid = threadIdx.x;
  st1[tid] = ws[WS_T1 + tid];
  __syncthreads();
  int jl = tid & 63, kc = tid >> 6;
  int j = blockIdx.x*64 + jl;
  float p = 0.f;
  #pragma unroll 8
  for (int i=0;i<64;i++){
    int k = kc*64 + i;
    p += st1[k]*W2[k*TEMB_ + j];
  }
  red[kc][jl] = p;
  __syncthreads();
  if (tid < 64){
    float a = b2[blockIdx.x*64 + tid];
    #pragma unroll
    for (int c=0;c<8;c++) a += red[c][tid];
    ws[WS_T2 + blockIdx.x*64 + tid] = a;
  }
}

// ---- split-K partial sums, wide contiguous chunks + NON-TEMPORAL weight streams ----
__global__ __launch_bounds__(256,2) void k_partial(
    const float* __restrict__ te,
    const float* __restrict__ WB, const float* __restrict__ MB,
    const float* __restrict__ WC, const float* __restrict__ MC,
    const float* __restrict__ WD, const float* __restrict__ MD,
    const float* __restrict__ WA, const float* __restrict__ MA,
    const float* __restrict__ Wdl, const float* __restrict__ Mdl,
    float* __restrict__ ws){
  __shared__ float st2[TEMB_];
  __shared__ float ste[SIN_];
  int tid = threadIdx.x;
  st2[tid] = ws[WS_T2 + tid];
  st2[tid+256] = ws[WS_T2 + tid + 256];
  if (tid < SIN_) ste[tid] = te[tid];
  __syncthreads();
  unsigned short* pbf = (unsigned short*)(ws + WS_PBF);
  int bb = blockIdx.x;
  if (bb < 512){
    int r = bb>>8, rem = bb&255, j = rem>>4, c = rem&15;
    const float4* W4 = (const float4*)(r ? WC : WB);
    const float4* base = W4 + (size_t)(c*GK)*16384 + j*1024 + tid;
    const float* coef = st2 + c*GK;
    nt4 a0={0,0,0,0}, a1={0,0,0,0}, a2={0,0,0,0}, a3={0,0,0,0};
    #pragma unroll 4
    for (int k=0;k<GK;k++){
      const float4* p = base + (size_t)k*16384;
      nt4 w0=ntload(p), w1=ntload(p+256), w2=ntload(p+512), w3=ntload(p+768);
      float cv = coef[k];
      a0 += cv*w0; a1 += cv*w1; a2 += cv*w2; a3 += cv*w3;
    }
    ushort4* dst = (ushort4*)pbf + (size_t)((r*NSL+j)*NCH + c)*1024;
    dst[tid]     = pack4nt(a0);
    dst[tid+256] = pack4nt(a1);
    dst[tid+512] = pack4nt(a2);
    dst[tid+768] = pack4nt(a3);
  } else if (bb < 640){
    int g = bb-512, r = g>>6, rem = g&63, j = rem>>2, cg = rem&3;
    const float4* M4 = (const float4*)(r ? MC : MB);
    const float4* base = M4 + (size_t)(cg*GK)*16384 + j*1024 + tid;
    const float* coef = ste + cg*GK;
    nt4 a0={0,0,0,0}, a1={0,0,0,0}, a2={0,0,0,0}, a3={0,0,0,0};
    #pragma unroll 4
    for (int k=0;k<GK;k++){
      const float4* p = base + (size_t)k*16384;
      nt4 w0=ntload(p), w1=ntload(p+256), w2=ntload(p+512), w3=ntload(p+768);
      float cv = coef[k];
      a0 += cv*w0; a1 += cv*w1; a2 += cv*w2; a3 += cv*w3;
    }
    ushort4* dst = (ushort4*)pbf + (size_t)524288 + (size_t)((r*NSL+j)*NGCH + cg)*1024;
    dst[tid]     = pack4nt(a0);
    dst[tid+256] = pack4nt(a1);
    dst[tid+512] = pack4nt(a2);
    dst[tid+768] = pack4nt(a3);
  } else if (bb < 656){
    int c = bb-640;
    const float4* base = (const float4*)WD + (size_t)(c*GK)*256 + tid;
    const float* coef = st2 + c*GK;
    nt4 a={0,0,0,0};
    #pragma unroll 4
    for (int k=0;k<GK;k++){
      nt4 w = ntload(base + (size_t)k*256);
      a += coef[k]*w;
    }
    float4 af = make_float4(a.x,a.y,a.z,a.w);
    ((float4*)(ws + WS_PD))[c*256 + tid] = af;
  } else if (bb < 660){
    int cg = bb-656;
    const float4* base = (const float4*)MD + (size_t)(cg*GK)*256 + tid;
    const float* coef = ste + cg*GK;
    nt4 a={0,0,0,0};
    #pragma unroll 4
    for (int k=0;k<GK;k++){
      nt4 w = ntload(base + (size_t)k*256);
      a += coef[k]*w;
    }
    float4 af = make_float4(a.x,a.y,a.z,a.w);
    ((float4*)(ws + WS_PDG))[cg*256 + tid] = af;
  } else {
    const float* Wm = (bb==660) ? WA : Wdl;
    const float* Mm = (bb==660) ? MA : Mdl;
    int outbase = (bb==660) ? WS_PA : WS_PDL;
    __shared__ float red[16][68];
    int q = tid&15, kr = tid>>4;
    float4 acc={0,0,0,0};
    const float4* W4 = (const float4*)Wm;
    #pragma unroll 4
    for (int it=0; it<32; ++it){
      int k = it*16 + kr;
      float4 w = W4[k*16 + q];
      float cv = st2[k];
      acc.x=fmaf(cv,w.x,acc.x); acc.y=fmaf(cv,w.y,acc.y); acc.z=fmaf(cv,w.z,acc.z); acc.w=fmaf(cv,w.w,acc.w);
    }
    red[kr][4*q+0]=acc.x; red[kr][4*q+1]=acc.y; red[kr][4*q+2]=acc.z; red[kr][4*q+3]=acc.w;
    __syncthreads();
    if (tid < 64){
      float s = 0.f;
      #pragma unroll
      for (int g=0;g<16;g++) s += red[g][tid];
      ws[outbase + tid] = s;
    }
    __syncthreads();
    float4 gac={0,0,0,0};
    const float4* M4 = (const float4*)Mm;
    #pragma unroll 4
    for (int it=0; it<8; ++it){
      int k = it*16 + kr;
      float4 w = M4[k*16 + q];
      float cv = ste[k];
      gac.x=fmaf(cv,w.x,gac.x); gac.y=fmaf(cv,w.y,gac.y); gac.z=fmaf(cv,w.z,gac.z); gac.w=fmaf(cv,w.w,gac.w);
    }
    red[kr][4*q+0]=gac.x; red[kr][4*q+1]=gac.y; red[kr][4*q+2]=gac.z; red[kr][4*q+3]=gac.w;
    __syncthreads();
    if (tid < 64){
      float s = 0.f;
      #pragma unroll
      for (int g=0;g<16;g++) s += red[g][tid];
      ws[outbase + 64 + tid] = s;
    }
  }
}

// ---- finalize: reduce bf16 partials, bias+gate, write bf16 BmT/CT + f32 D; A/delta/fac ----
__global__ __launch_bounds__(256) void k_finalize(
    const float* __restrict__ bB, const float* __restrict__ mB,
    const float* __restrict__ bC, const float* __restrict__ mC,
    const float* __restrict__ bD, const float* __restrict__ mD,
    const float* __restrict__ bA_, const float* __restrict__ mA_,
    const float* __restrict__ bdl, const float* __restrict__ mdl,
    float* __restrict__ ws){
  int tid = threadIdx.x, bb = blockIdx.x;
  const ushort4* pbf4 = (const ushort4*)(ws + WS_PBF);
  unsigned short* bmth = (unsigned short*)(ws + WS_BMTH);
  unsigned short* cth  = (unsigned short*)(ws + WS_CTH);
  if (bb < 128){
    int r = bb>>6;
    int q = (bb&63)*256 + tid;        // f4 idx within region [0,16384)
    int j = q>>10, p = q&1023;
    float4 a = {0,0,0,0};
    size_t wbase = ((size_t)(r*NSL+j)*NCH)*1024 + p;
    #pragma unroll
    for (int c=0;c<NCH;c++){
      ushort4 v = pbf4[wbase + (size_t)c*1024];
      a.x += bf2f(v.x); a.y += bf2f(v.y); a.z += bf2f(v.z); a.w += bf2f(v.w);
    }
    float4 g = {0,0,0,0};
    size_t gbase = (size_t)524288 + ((size_t)(r*NSL+j)*NGCH)*1024 + p;
    #pragma unroll
    for (int cg=0;cg<NGCH;cg++){
      ushort4 v = pbf4[gbase + (size_t)cg*1024];
      g.x += bf2f(v.x); g.y += bf2f(v.y); g.z += bf2f(v.z); g.w += bf2f(v.w);
    }
    if (r == 0){
      float4 b4 = ((const float4*)bB)[q];
      float4 m4 = ((const float4*)mB)[q];
      float4 sg = sig4_(make_float4(g.x+m4.x, g.y+m4.y, g.z+m4.z, g.w+m4.w));
      float4 v = make_float4((a.x+b4.x)*sg.x,(a.y+b4.y)*sg.y,(a.z+b4.z)*sg.z,(a.w+b4.w)*sg.w);
      int o = q*4; int s = o>>10; int e = o&1023;
      bmth[(e+0)*64 + s] = f2bf(v.x);
      bmth[(e+1)*64 + s] = f2bf(v.y);
      bmth[(e+2)*64 + s] = f2bf(v.z);
      bmth[(e+3)*64 + s] = f2bf(v.w);
    } else {
      float4 b4 = ((const float4*)bC)[q];
      float4 m4 = ((const float4*)mC)[q];
      float4 sg = sig4_(make_float4(g.x+m4.x, g.y+m4.y, g.z+m4.z, g.w+m4.w));
      float4 v = make_float4((a.x+b4.x)*sg.x,(a.y+b4.y)*sg.y,(a.z+b4.z)*sg.z,(a.w+b4.w)*sg.w);
      int o = q*4; int e = o>>6; int s = o&63;
      cth[(s+0)*1024 + e] = f2bf(v.x);
      cth[(s+1)*1024 + e] = f2bf(v.y);
      cth[(s+2)*1024 + e] = f2bf(v.z);
      cth[(s+3)*1024 + e] = f2bf(v.w);
    }
  } else if (bb == 128){
    float4 a = {0,0,0,0};
    #pragma unroll
    for (int c=0;c<NCH;c++){
      float4 v = ((const float4*)(ws + WS_PD))[c*256 + tid];
      a.x+=v.x; a.y+=v.y; a.z+=v.z; a.w+=v.w;
    }
    float4 g = {0,0,0,0};
    #pragma unroll
    for (int cg=0;cg<NGCH;cg++){
      float4 v = ((const float4*)(ws + WS_PDG))[cg*256 + tid];
      g.x+=v.x; g.y+=v.y; g.z+=v.z; g.w+=v.w;
    }
    float4 b4 = ((const float4*)bD)[tid];
    float4 m4 = ((const float4*)mD)[tid];
    float4 sg = sig4_(make_float4(g.x+m4.x, g.y+m4.y, g.z+m4.z, g.w+m4.w));
    float4 v = make_float4((a.x+b4.x)*sg.x,(a.y+b4.y)*sg.y,(a.z+b4.z)*sg.z,(a.w+b4.w)*sg.w);
    ((float4*)(ws + WS_D))[tid] = v;
  } else {
    __shared__ float sda[64];
    if (tid < 64){
      int s = tid;
      float A = -softplusf_(ws[WS_PA+s] + bA_[s]) * sigmoidf_(ws[WS_PA+64+s] + mA_[s]);
      float delta = (softplusf_(ws[WS_PDL+s] + bdl[s]) + 1e-4f) * sigmoidf_(ws[WS_PDL+64+s] + mdl[s]);
      float da = delta * A;
      sda[s] = da;
      ws[WS_DELTA+s] = delta;
      ws[WS_ABAR+s]  = expf(da);
      ws[WS_EL+s]    = expf((float)L_*da);
    }
    __syncthreads();
    for (int idx=tid; idx<L_*S_; idx+=256){
      int tl = idx>>6, s = idx&63;
      ws[WS_FAC+idx] = expf((float)(tl+1)*sda[s]);
    }
  }
}

// ---- per-(b,chunk of 64 rows): u = delta ⊙ (x @ Bm^T), zero-state local scan ----
__global__ __launch_bounds__(256) void k_scan(const float* __restrict__ x, float* __restrict__ ws){
  __shared__ float Xs[64][68];     // [trow][k]
  __shared__ float BsT[64][68];    // [k][s]
  __shared__ float Us[64][65];     // [trow][s]
  __shared__ float sdl[S_], sab[S_];
  int tid = threadIdx.x;
  int bb = blockIdx.x;                       // b*NC_ + c  (256 blocks)
  int row0 = (bb>>6)*T_ + (bb&63)*L_;
  if (tid<64){ sdl[tid]=ws[WS_DELTA+tid]; sab[tid]=ws[WS_ABAR+tid]; }
  float acc[4][4];
  #pragma unroll
  for (int i=0;i<4;i++)
    #pragma unroll
    for (int j=0;j<4;j++) acc[i][j]=0.f;
  int ty = tid>>4, tx = tid&15;
  const float4* x4 = (const float4*)x;
  const ushort4* bm4 = (const ushort4*)(ws + WS_BMTH);
  for (int kk=0; kk<EMB_; kk+=64){
    #pragma unroll
    for (int t=0;t<4;t++){
      int fl = t*256+tid; int rr = fl>>4, cq = fl&15;
      float4 xv = x4[(size_t)(row0+rr)*256 + (kk>>2) + cq];
      *(float4*)&Xs[rr][cq*4] = xv;
      ushort4 hv = bm4[(size_t)(kk+rr)*16 + cq];
      *(float4*)&BsT[rr][cq*4] = make_float4(bf2f(hv.x),bf2f(hv.y),bf2f(hv.z),bf2f(hv.w));
    }
    __syncthreads();
    #pragma unroll 8
    for (int k=0;k<64;k++){
      float4 b4 = *(const float4*)&BsT[k][4*tx];
      float x0 = Xs[4*ty+0][k], x1 = Xs[4*ty+1][k], x2 = Xs[4*ty+2][k], x3 = Xs[4*ty+3][k];
      acc[0][0]+=x0*b4.x; acc[0][1]+=x0*b4.y; acc[0][2]+=x0*b4.z; acc[0][3]+=x0*b4.w;
      acc[1][0]+=x1*b4.x; acc[1][1]+=x1*b4.y; acc[1][2]+=x1*b4.z; acc[1][3]+=x1*b4.w;
      acc[2][0]+=x2*b4.x; acc[2][1]+=x2*b4.y; acc[2][2]+=x2*b4.z; acc[2][3]+=x2*b4.w;
      acc[3][0]+=x3*b4.x; acc[3][1]+=x3*b4.y; acc[3][2]+=x3*b4.z; acc[3][3]+=x3*b4.w;
    }
    __syncthreads();
  }
  #pragma unroll
  for (int i=0;i<4;i++)
    #pragma unroll
    for (int j=0;j<4;j++)
      Us[4*ty+i][4*tx+j] = acc[i][j]*sdl[4*tx+j];
  __syncthreads();
  if (tid<64){
    unsigned short* hh = (unsigned short*)(ws + WS_HLOCH);
    int s = tid; float h = 0.f, ab = sab[s];
    #pragma unroll 8
    for (int t=0;t<L_;t++){
      h = fmaf(ab, h, Us[t][s]);
      hh[(size_t)(row0+t)*S_ + s] = f2bf(h);
    }
    ws[WS_CHEND + bb*S_ + s] = h;
  }
}

// ---- chain chunk boundary states (LDS-staged) ----
__global__ __launch_bounds__(256) void k_carry(float* __restrict__ ws){
  __shared__ float ch[B_*NC_*S_];            // 16384 f = 64 KB
  int tid = threadIdx.x;
  const float4* src = (const float4*)(ws + WS_CHEND);
  float4* chv = (float4*)ch;
  for (int i=tid;i<4096;i+=256) chv[i] = src[i];
  __syncthreads();
  int b = tid>>6, s = tid&63;
  float el = ws[WS_EL + s];
  float carry = 0.f;
  #pragma unroll 8
  for (int c=0;c<NC_;c++){
    int idx = (b*NC_ + c)*S_ + s;
    float v = ch[idx];
    ch[idx] = carry;                         // in-place: becomes CARRY
    carry = fmaf(el, carry, v);
  }
  __syncthreads();
  float4* dst = (float4*)(ws + WS_CARRY);
  for (int i=tid;i<4096;i+=256) dst[i] = chv[i];
}

// ---- out = (hloc + fac*carry) @ C^T + D*x  (128-row x 64-e tiles) ----
__global__ __launch_bounds__(256) void k_out(const float* __restrict__ x,
                                             const float* __restrict__ ws,
                                             float* __restrict__ out){
  __shared__ float Cts[64][68];    // [s][elocal]
  __shared__ float Hs[128][68];    // [trow][s]
  int tid = threadIdx.x;
  int bb = blockIdx.x;
  int rt = bb & 127, et = bb >> 7;           // 128 row tiles x 16 e-tiles
  int row0 = rt*128, e0 = et*64;
  int b = row0 >> 12;
  int cbase = b*NC_ + ((row0 & (T_-1)) >> 6);
  const ushort4* hl4h = (const ushort4*)(ws + WS_HLOCH);
  const ushort4* cth4 = (const ushort4*)(ws + WS_CTH);
  const float4* fc4 = (const float4*)(ws + WS_FAC);
  const float4* cr4 = (const float4*)(ws + WS_CARRY);
  #pragma unroll
  for (int t=0;t<8;t++){
    int fl = t*256+tid; int rr = fl>>4, q = fl&15;
    ushort4 h4 = hl4h[(size_t)(row0+rr)*16 + q];
    float4 f = fc4[(rr & (L_-1))*16 + q];
    float4 c = cr4[(cbase + (rr>>6))*16 + q];
    float4 hv = make_float4(bf2f(h4.x)+f.x*c.x, bf2f(h4.y)+f.y*c.y,
                            bf2f(h4.z)+f.z*c.z, bf2f(h4.w)+f.w*c.w);
    *(float4*)&Hs[rr][q*4] = hv;
  }
  #pragma unroll
  for (int t=0;t<4;t++){
    int fl = t*256+tid; int rr = fl>>4, q = fl&15;
    ushort4 ct4 = cth4[(size_t)rr*256 + (e0>>2) + q];
    *(float4*)&Cts[rr][q*4] = make_float4(bf2f(ct4.x),bf2f(ct4.y),bf2f(ct4.z),bf2f(ct4.w));
  }
  __syncthreads();
  int ty = tid>>4, tx = tid&15;              // 16 row-groups x 16 col-groups
  float acc[8][4];
  #pragma unroll
  for (int i=0;i<8;i++)
    #pragma unroll
    for (int j=0;j<4;j++) acc[i][j]=0.f;
  #pragma unroll 4
  for (int s=0;s<64;s++){
    float4 c4 = *(const float4*)&Cts[s][4*tx];
    #pragma unroll
    for (int i=0;i<8;i++){
      float hv = Hs[8*ty+i][s];
      acc[i][0]+=hv*c4.x; acc[i][1]+=hv*c4.y; acc[i][2]+=hv*c4.z; acc[i][3]+=hv*c4.w;
    }
  }
  float4 d4 = ((const float4*)(ws + WS_D))[(e0>>2) + tx];
  #pragma unroll
  for (int i=0;i<8;i++){
    int row = row0 + 8*ty + i;
    float4 x4v = reinterpret_cast<const float4*>(x + (size_t)row*EMB_ + e0)[tx];
    float4 o;
    o.x = acc[i][0] + d4.x*x4v.x;
    o.y = acc[i][1] + d4.y*x4v.y;
    o.z = acc[i][2] + d4.z*x4v.z;
    o.w = acc[i][3] + d4.w*x4v.w;
    reinterpret_cast<float4*>(out + (size_t)row*EMB_ + e0)[tx] = o;
  }
}

extern "C" void kernel_launch(void* const* d_in, const int* in_sizes, int n_in,
                              void* d_out, int out_size, void* d_ws, size_t ws_size,
                              hipStream_t stream){
  const float* te  = (const float*)d_in[0];
  const float* x   = (const float*)d_in[1];
  const float* W1  = (const float*)d_in[2];
  const float* b1  = (const float*)d_in[3];
  const float* W2  = (const float*)d_in[4];
  const float* b2  = (const float*)d_in[5];
  const float* WA  = (const float*)d_in[6];
  const float* bA  = (const float*)d_in[7];
  const float* WB  = (const float*)d_in[8];
  const float* bB  = (const float*)d_in[9];
  const float* WC  = (const float*)d_in[10];
  const float* bC  = (const float*)d_in[11];
  const float* WD  = (const float*)d_in[12];
  const float* bD  = (const float*)d_in[13];
  const float* Wdl = (const float*)d_in[14];
  const float* bdl = (const float*)d_in[15];
  const float* MA  = (const float*)d_in[16];
  const float* mA  = (const float*)d_in[17];
  const float* MB  = (const float*)d_in[18];
  const float* mB  = (const float*)d_in[19];
  const float* MC  = (const float*)d_in[20];
  const float* mC  = (const float*)d_in[21];
  const float* MD  = (const float*)d_in[22];
  const float* mD  = (const float*)d_in[23];
  const float* Mdl = (const float*)d_in[24];
  const float* mdl = (const float*)d_in[25];
  float* ws  = (float*)d_ws;
  float* out = (float*)d_out;

  k_t1<<<8,64,0,stream>>>(te, W1, b1, ws);
  k_t2<<<8,512,0,stream>>>(W2, b2, ws);
  k_partial<<<662,256,0,stream>>>(te, WB,MB, WC,MC, WD,MD, WA,MA, Wdl,Mdl, ws);
  k_finalize<<<130,256,0,stream>>>(bB,mB, bC,mC, bD,mD, bA,mA, bdl,mdl, ws);
  k_scan<<<256,256,0,stream>>>(x, ws);
  k_carry<<<1,256,0,stream>>>(ws);
  k_out<<<2048,256,0,stream>>>(x, ws, out);
}

// Round 9
// 159.109 us; speedup vs baseline: 1.2165x; 1.0032x over previous
//
#include <hip/hip_runtime.h>
#include <math.h>

#define SIN_ 128
#define TEMB_ 512
#define EMB_ 1024
#define S_ 64
#define B_ 4
#define T_ 4096
#define NROW (B_*T_)          // 16384
#define L_ 64                 // scan chunk length
#define NC_ (T_/L_)           // 64 chunks per batch row

#define GK 32                 // K-rows per partial block
#define NSL 32                // column slices per region (slice = 512 f4 = 2048 floats = 8 KB)
#define SLW 512               // slice width in f4
#define NCH 16                // W chunks (512/GK)
#define NGCH 4                // gate chunks (128/GK)

// workspace layout (float offsets)
#define WS_T1     0
#define WS_T2     512
#define WS_DELTA  1024
#define WS_ABAR   1088
#define WS_EL     1152
#define WS_FAC    1216                    // L_*S_ = 4096
#define WS_D      5312                    // 1024
#define WS_BMTH   6336                    // bf16 BmT[e][s]: 65536 ushorts = 32768 slots
#define WS_CTH    39104                   // bf16 CT[s][e]:  65536 ushorts = 32768 slots
#define WS_PD     71872                   // 16*1024 f32
#define WS_PDG    88256                   // 4*1024 f32
#define WS_PA     92352                   // A sums [64] + gate [64]
#define WS_PDL    92480                   // dl sums [64] + gate [64]
#define WS_PBF    92608                   // bf16 partials: 2,621,440 ushorts = 1,310,720 slots
// W partials: ushort4 idx 0      .. 524288   ([2][32][16][512])
// G partials: ushort4 idx 524288 .. 655360   ([2][32][4][512])
#define WS_HLOCH  92608                   // overlay on PBF: bf16 hloc[NROW][S] (524288 slots)
#define WS_CHEND  1403328                 // B_*NC_*S_ = 16384 f32
#define WS_CARRY  1419712                 // 16384 f32
// total 1,436,096 floats = 5.74 MB

typedef float nt4 __attribute__((ext_vector_type(4)));

__device__ __forceinline__ float sigmoidf_(float x){ return 1.f/(1.f+expf(-x)); }
__device__ __forceinline__ float softplusf_(float x){ return x>20.f ? x : log1pf(expf(x)); }
__device__ __forceinline__ float4 sig4_(float4 g){
  float4 r; r.x=sigmoidf_(g.x); r.y=sigmoidf_(g.y); r.z=sigmoidf_(g.z); r.w=sigmoidf_(g.w); return r;
}
__device__ __forceinline__ unsigned short f2bf(float x){
  unsigned int u = __float_as_uint(x);
  unsigned int r = (u + 0x7FFFu + ((u>>16)&1u)) >> 16;
  return (unsigned short)r;
}
__device__ __forceinline__ ushort4 pack4nt(nt4 v){
  return make_ushort4(f2bf(v.x),f2bf(v.y),f2bf(v.z),f2bf(v.w));
}
__device__ __forceinline__ float bf2f(unsigned short h){
  return __uint_as_float(((unsigned int)h)<<16);
}
__device__ __forceinline__ nt4 ntload(const float4* p){
  return __builtin_nontemporal_load((const nt4*)p);
}
__device__ __forceinline__ void ntstore(float* p, float4 v){
  nt4 t = {v.x, v.y, v.z, v.w};
  __builtin_nontemporal_store(t, (nt4*)p);
}

// ---- t1 = silu(te @ W1 + b1) ----
__global__ void k_t1(const float* __restrict__ te, const float* __restrict__ W1,
                     const float* __restrict__ b1, float* __restrict__ ws){
  __shared__ float ste[SIN_];
  int tid = threadIdx.x;                 // 64 threads, 8 blocks
  ste[tid] = te[tid]; ste[tid+64] = te[tid+64];
  __syncthreads();
  int j = blockIdx.x*64 + tid;
  float a = b1[j];
  #pragma unroll 16
  for (int i=0;i<SIN_;i++) a += ste[i]*W1[i*TEMB_ + j];
  ws[WS_T1 + j] = a * sigmoidf_(a);
}

// ---- t2 = t1 @ W2 + b2 ----
__global__ __launch_bounds__(512) void k_t2(const float* __restrict__ W2,
                                            const float* __restrict__ b2,
                                            float* __restrict__ ws){
  __shared__ float st1[TEMB_];
  __shared__ float red[8][64];
  int tid = threadIdx.x;
  st1[tid] = ws[WS_T1 + tid];
  __syncthreads();
  int jl = tid & 63, kc = tid >> 6;
  int j = blockIdx.x*64 + jl;
  float p = 0.f;
  #pragma unroll 8
  for (int i=0;i<64;i++){
    int k = kc*64 + i;
    p += st1[k]*W2[k*TEMB_ + j];
  }
  red[kc][jl] = p;
  __syncthreads();
  if (tid < 64){
    float a = b2[blockIdx.x*64 + tid];
    #pragma unroll
    for (int c=0;c<8;c++) a += red[c][tid];
    ws[WS_T2 + blockIdx.x*64 + tid] = a;
  }
}

// ---- split-K partial sums: NT weight streams, 8 KB slices, 1302 blocks ----
// blocks 0..1023    : B/C W-part.  r=bb>>9, j=(bb&511)>>4 (32 slices), c=bb&15
// blocks 1024..1279 : B/C gates.   g=bb-1024: r=g>>7, j=(g&127)>>2, cg=g&3
// blocks 1280..1295 : D W-part;  1296..1299: D gates; 1300: A; 1301: dl
__global__ __launch_bounds__(256,2) void k_partial(
    const float* __restrict__ te,
    const float* __restrict__ WB, const float* __restrict__ MB,
    const float* __restrict__ WC, const float* __restrict__ MC,
    const float* __restrict__ WD, const float* __restrict__ MD,
    const float* __restrict__ WA, const float* __restrict__ MA,
    const float* __restrict__ Wdl, const float* __restrict__ Mdl,
    float* __restrict__ ws){
  __shared__ float st2[TEMB_];
  __shared__ float ste[SIN_];
  int tid = threadIdx.x;
  st2[tid] = ws[WS_T2 + tid];
  st2[tid+256] = ws[WS_T2 + tid + 256];
  if (tid < SIN_) ste[tid] = te[tid];
  __syncthreads();
  unsigned short* pbf = (unsigned short*)(ws + WS_PBF);
  int bb = blockIdx.x;
  if (bb < 1024){
    int r = bb>>9, rem = bb&511, j = rem>>4, c = rem&15;
    const float4* W4 = (const float4*)(r ? WC : WB);
    const float4* base = W4 + (size_t)(c*GK)*16384 + j*SLW + tid;
    const float* coef = st2 + c*GK;
    nt4 a0={0,0,0,0}, a1={0,0,0,0};
    #pragma unroll 8
    for (int k=0;k<GK;k++){
      const float4* p = base + (size_t)k*16384;
      nt4 w0=ntload(p), w1=ntload(p+256);
      float cv = coef[k];
      a0 += cv*w0; a1 += cv*w1;
    }
    ushort4* dst = (ushort4*)pbf + (size_t)((r*NSL+j)*NCH + c)*SLW;
    dst[tid]     = pack4nt(a0);
    dst[tid+256] = pack4nt(a1);
  } else if (bb < 1280){
    int g = bb-1024, r = g>>7, rem = g&127, j = rem>>2, cg = rem&3;
    const float4* M4 = (const float4*)(r ? MC : MB);
    const float4* base = M4 + (size_t)(cg*GK)*16384 + j*SLW + tid;
    const float* coef = ste + cg*GK;
    nt4 a0={0,0,0,0}, a1={0,0,0,0};
    #pragma unroll 8
    for (int k=0;k<GK;k++){
      const float4* p = base + (size_t)k*16384;
      nt4 w0=ntload(p), w1=ntload(p+256);
      float cv = coef[k];
      a0 += cv*w0; a1 += cv*w1;
    }
    ushort4* dst = (ushort4*)pbf + (size_t)524288 + (size_t)((r*NSL+j)*NGCH + cg)*SLW;
    dst[tid]     = pack4nt(a0);
    dst[tid+256] = pack4nt(a1);
  } else if (bb < 1296){
    int c = bb-1280;
    const float4* base = (const float4*)WD + (size_t)(c*GK)*256 + tid;
    const float* coef = st2 + c*GK;
    nt4 a={0,0,0,0};
    #pragma unroll 4
    for (int k=0;k<GK;k++){
      nt4 w = ntload(base + (size_t)k*256);
      a += coef[k]*w;
    }
    float4 af = make_float4(a.x,a.y,a.z,a.w);
    ((float4*)(ws + WS_PD))[c*256 + tid] = af;
  } else if (bb < 1300){
    int cg = bb-1296;
    const float4* base = (const float4*)MD + (size_t)(cg*GK)*256 + tid;
    const float* coef = ste + cg*GK;
    nt4 a={0,0,0,0};
    #pragma unroll 4
    for (int k=0;k<GK;k++){
      nt4 w = ntload(base + (size_t)k*256);
      a += coef[k]*w;
    }
    float4 af = make_float4(a.x,a.y,a.z,a.w);
    ((float4*)(ws + WS_PDG))[cg*256 + tid] = af;
  } else {
    const float* Wm = (bb==1300) ? WA : Wdl;
    const float* Mm = (bb==1300) ? MA : Mdl;
    int outbase = (bb==1300) ? WS_PA : WS_PDL;
    __shared__ float red[16][68];
    int q = tid&15, kr = tid>>4;
    float4 acc={0,0,0,0};
    const float4* W4 = (const float4*)Wm;
    #pragma unroll 4
    for (int it=0; it<32; ++it){
      int k = it*16 + kr;
      float4 w = W4[k*16 + q];
      float cv = st2[k];
      acc.x=fmaf(cv,w.x,acc.x); acc.y=fmaf(cv,w.y,acc.y); acc.z=fmaf(cv,w.z,acc.z); acc.w=fmaf(cv,w.w,acc.w);
    }
    red[kr][4*q+0]=acc.x; red[kr][4*q+1]=acc.y; red[kr][4*q+2]=acc.z; red[kr][4*q+3]=acc.w;
    __syncthreads();
    if (tid < 64){
      float s = 0.f;
      #pragma unroll
      for (int g=0;g<16;g++) s += red[g][tid];
      ws[outbase + tid] = s;
    }
    __syncthreads();
    float4 gac={0,0,0,0};
    const float4* M4 = (const float4*)Mm;
    #pragma unroll 4
    for (int it=0; it<8; ++it){
      int k = it*16 + kr;
      float4 w = M4[k*16 + q];
      float cv = ste[k];
      gac.x=fmaf(cv,w.x,gac.x); gac.y=fmaf(cv,w.y,gac.y); gac.z=fmaf(cv,w.z,gac.z); gac.w=fmaf(cv,w.w,gac.w);
    }
    red[kr][4*q+0]=gac.x; red[kr][4*q+1]=gac.y; red[kr][4*q+2]=gac.z; red[kr][4*q+3]=gac.w;
    __syncthreads();
    if (tid < 64){
      float s = 0.f;
      #pragma unroll
      for (int g=0;g<16;g++) s += red[g][tid];
      ws[outbase + 64 + tid] = s;
    }
  }
}

// ---- finalize: reduce bf16 partials, bias+gate, write bf16 BmT/CT + f32 D; A/delta/fac ----
__global__ __launch_bounds__(256) void k_finalize(
    const float* __restrict__ bB, const float* __restrict__ mB,
    const float* __restrict__ bC, const float* __restrict__ mC,
    const float* __restrict__ bD, const float* __restrict__ mD,
    const float* __restrict__ bA_, const float* __restrict__ mA_,
    const float* __restrict__ bdl, const float* __restrict__ mdl,
    float* __restrict__ ws){
  int tid = threadIdx.x, bb = blockIdx.x;
  const ushort4* pbf4 = (const ushort4*)(ws + WS_PBF);
  unsigned short* bmth = (unsigned short*)(ws + WS_BMTH);
  unsigned short* cth  = (unsigned short*)(ws + WS_CTH);
  if (bb < 128){
    int r = bb>>6;
    int q = (bb&63)*256 + tid;        // f4 idx within region [0,16384)
    int j = q>>9, p = q&511;          // slice (512 f4) / offset
    float4 a = {0,0,0,0};
    size_t wbase = ((size_t)(r*NSL+j)*NCH)*SLW + p;
    #pragma unroll
    for (int c=0;c<NCH;c++){
      ushort4 v = pbf4[wbase + (size_t)c*SLW];
      a.x += bf2f(v.x); a.y += bf2f(v.y); a.z += bf2f(v.z); a.w += bf2f(v.w);
    }
    float4 g = {0,0,0,0};
    size_t gbase = (size_t)524288 + ((size_t)(r*NSL+j)*NGCH)*SLW + p;
    #pragma unroll
    for (int cg=0;cg<NGCH;cg++){
      ushort4 v = pbf4[gbase + (size_t)cg*SLW];
      g.x += bf2f(v.x); g.y += bf2f(v.y); g.z += bf2f(v.z); g.w += bf2f(v.w);
    }
    if (r == 0){
      float4 b4 = ((const float4*)bB)[q];
      float4 m4 = ((const float4*)mB)[q];
      float4 sg = sig4_(make_float4(g.x+m4.x, g.y+m4.y, g.z+m4.z, g.w+m4.w));
      float4 v = make_float4((a.x+b4.x)*sg.x,(a.y+b4.y)*sg.y,(a.z+b4.z)*sg.z,(a.w+b4.w)*sg.w);
      int o = q*4; int s = o>>10; int e = o&1023;
      bmth[(e+0)*64 + s] = f2bf(v.x);
      bmth[(e+1)*64 + s] = f2bf(v.y);
      bmth[(e+2)*64 + s] = f2bf(v.z);
      bmth[(e+3)*64 + s] = f2bf(v.w);
    } else {
      float4 b4 = ((const float4*)bC)[q];
      float4 m4 = ((const float4*)mC)[q];
      float4 sg = sig4_(make_float4(g.x+m4.x, g.y+m4.y, g.z+m4.z, g.w+m4.w));
      float4 v = make_float4((a.x+b4.x)*sg.x,(a.y+b4.y)*sg.y,(a.z+b4.z)*sg.z,(a.w+b4.w)*sg.w);
      int o = q*4; int e = o>>6; int s = o&63;
      cth[(s+0)*1024 + e] = f2bf(v.x);
      cth[(s+1)*1024 + e] = f2bf(v.y);
      cth[(s+2)*1024 + e] = f2bf(v.z);
      cth[(s+3)*1024 + e] = f2bf(v.w);
    }
  } else if (bb == 128){
    float4 a = {0,0,0,0};
    #pragma unroll
    for (int c=0;c<NCH;c++){
      float4 v = ((const float4*)(ws + WS_PD))[c*256 + tid];
      a.x+=v.x; a.y+=v.y; a.z+=v.z; a.w+=v.w;
    }
    float4 g = {0,0,0,0};
    #pragma unroll
    for (int cg=0;cg<NGCH;cg++){
      float4 v = ((const float4*)(ws + WS_PDG))[cg*256 + tid];
      g.x+=v.x; g.y+=v.y; g.z+=v.z; g.w+=v.w;
    }
    float4 b4 = ((const float4*)bD)[tid];
    float4 m4 = ((const float4*)mD)[tid];
    float4 sg = sig4_(make_float4(g.x+m4.x, g.y+m4.y, g.z+m4.z, g.w+m4.w));
    float4 v = make_float4((a.x+b4.x)*sg.x,(a.y+b4.y)*sg.y,(a.z+b4.z)*sg.z,(a.w+b4.w)*sg.w);
    ((float4*)(ws + WS_D))[tid] = v;
  } else {
    __shared__ float sda[64];
    if (tid < 64){
      int s = tid;
      float A = -softplusf_(ws[WS_PA+s] + bA_[s]) * sigmoidf_(ws[WS_PA+64+s] + mA_[s]);
      float delta = (softplusf_(ws[WS_PDL+s] + bdl[s]) + 1e-4f) * sigmoidf_(ws[WS_PDL+64+s] + mdl[s]);
      float da = delta * A;
      sda[s] = da;
      ws[WS_DELTA+s] = delta;
      ws[WS_ABAR+s]  = expf(da);
      ws[WS_EL+s]    = expf((float)L_*da);
    }
    __syncthreads();
    for (int idx=tid; idx<L_*S_; idx+=256){
      int tl = idx>>6, s = idx&63;
      ws[WS_FAC+idx] = expf((float)(tl+1)*sda[s]);
    }
  }
}

// ---- per-(b,chunk of 64 rows): u = delta ⊙ (x @ Bm^T), zero-state local scan ----
__global__ __launch_bounds__(256) void k_scan(const float* __restrict__ x, float* __restrict__ ws){
  __shared__ float Xs[64][68];     // [trow][k]
  __shared__ float BsT[64][68];    // [k][s]
  __shared__ float Us[64][65];     // [trow][s]
  __shared__ float sdl[S_], sab[S_];
  int tid = threadIdx.x;
  int bb = blockIdx.x;                       // b*NC_ + c  (256 blocks)
  int row0 = (bb>>6)*T_ + (bb&63)*L_;
  if (tid<64){ sdl[tid]=ws[WS_DELTA+tid]; sab[tid]=ws[WS_ABAR+tid]; }
  float acc[4][4];
  #pragma unroll
  for (int i=0;i<4;i++)
    #pragma unroll
    for (int j=0;j<4;j++) acc[i][j]=0.f;
  int ty = tid>>4, tx = tid&15;
  const float4* x4 = (const float4*)x;
  const ushort4* bm4 = (const ushort4*)(ws + WS_BMTH);
  for (int kk=0; kk<EMB_; kk+=64){
    #pragma unroll
    for (int t=0;t<4;t++){
      int fl = t*256+tid; int rr = fl>>4, cq = fl&15;
      float4 xv = x4[(size_t)(row0+rr)*256 + (kk>>2) + cq];
      *(float4*)&Xs[rr][cq*4] = xv;
      ushort4 hv = bm4[(size_t)(kk+rr)*16 + cq];
      *(float4*)&BsT[rr][cq*4] = make_float4(bf2f(hv.x),bf2f(hv.y),bf2f(hv.z),bf2f(hv.w));
    }
    __syncthreads();
    #pragma unroll 8
    for (int k=0;k<64;k++){
      float4 b4 = *(const float4*)&BsT[k][4*tx];
      float x0 = Xs[4*ty+0][k], x1 = Xs[4*ty+1][k], x2 = Xs[4*ty+2][k], x3 = Xs[4*ty+3][k];
      acc[0][0]+=x0*b4.x; acc[0][1]+=x0*b4.y; acc[0][2]+=x0*b4.z; acc[0][3]+=x0*b4.w;
      acc[1][0]+=x1*b4.x; acc[1][1]+=x1*b4.y; acc[1][2]+=x1*b4.z; acc[1][3]+=x1*b4.w;
      acc[2][0]+=x2*b4.x; acc[2][1]+=x2*b4.y; acc[2][2]+=x2*b4.z; acc[2][3]+=x2*b4.w;
      acc[3][0]+=x3*b4.x; acc[3][1]+=x3*b4.y; acc[3][2]+=x3*b4.z; acc[3][3]+=x3*b4.w;
    }
    __syncthreads();
  }
  #pragma unroll
  for (int i=0;i<4;i++)
    #pragma unroll
    for (int j=0;j<4;j++)
      Us[4*ty+i][4*tx+j] = acc[i][j]*sdl[4*tx+j];
  __syncthreads();
  if (tid<64){
    unsigned short* hh = (unsigned short*)(ws + WS_HLOCH);
    int s = tid; float h = 0.f, ab = sab[s];
    #pragma unroll 8
    for (int t=0;t<L_;t++){
      h = fmaf(ab, h, Us[t][s]);
      hh[(size_t)(row0+t)*S_ + s] = f2bf(h);
    }
    ws[WS_CHEND + bb*S_ + s] = h;
  }
}

// ---- chain chunk boundary states (LDS-staged) ----
__global__ __launch_bounds__(256) void k_carry(float* __restrict__ ws){
  __shared__ float ch[B_*NC_*S_];            // 16384 f = 64 KB
  int tid = threadIdx.x;
  const float4* src = (const float4*)(ws + WS_CHEND);
  float4* chv = (float4*)ch;
  for (int i=tid;i<4096;i+=256) chv[i] = src[i];
  __syncthreads();
  int b = tid>>6, s = tid&63;
  float el = ws[WS_EL + s];
  float carry = 0.f;
  #pragma unroll 8
  for (int c=0;c<NC_;c++){
    int idx = (b*NC_ + c)*S_ + s;
    float v = ch[idx];
    ch[idx] = carry;                         // in-place: becomes CARRY
    carry = fmaf(el, carry, v);
  }
  __syncthreads();
  float4* dst = (float4*)(ws + WS_CARRY);
  for (int i=tid;i<4096;i+=256) dst[i] = chv[i];
}

// ---- out = (hloc + fac*carry) @ C^T + D*x  (128-row x 64-e tiles, NT stores) ----
__global__ __launch_bounds__(256) void k_out(const float* __restrict__ x,
                                             const float* __restrict__ ws,
                                             float* __restrict__ out){
  __shared__ float Cts[64][68];    // [s][elocal]
  __shared__ float Hs[128][68];    // [trow][s]
  int tid = threadIdx.x;
  int bb = blockIdx.x;
  int rt = bb & 127, et = bb >> 7;           // 128 row tiles x 16 e-tiles
  int row0 = rt*128, e0 = et*64;
  int b = row0 >> 12;
  int cbase = b*NC_ + ((row0 & (T_-1)) >> 6);
  const ushort4* hl4h = (const ushort4*)(ws + WS_HLOCH);
  const ushort4* cth4 = (const ushort4*)(ws + WS_CTH);
  const float4* fc4 = (const float4*)(ws + WS_FAC);
  const float4* cr4 = (const float4*)(ws + WS_CARRY);
  #pragma unroll
  for (int t=0;t<8;t++){
    int fl = t*256+tid; int rr = fl>>4, q = fl&15;
    ushort4 h4 = hl4h[(size_t)(row0+rr)*16 + q];
    float4 f = fc4[(rr & (L_-1))*16 + q];
    float4 c = cr4[(cbase + (rr>>6))*16 + q];
    float4 hv = make_float4(bf2f(h4.x)+f.x*c.x, bf2f(h4.y)+f.y*c.y,
                            bf2f(h4.z)+f.z*c.z, bf2f(h4.w)+f.w*c.w);
    *(float4*)&Hs[rr][q*4] = hv;
  }
  #pragma unroll
  for (int t=0;t<4;t++){
    int fl = t*256+tid; int rr = fl>>4, q = fl&15;
    ushort4 ct4 = cth4[(size_t)rr*256 + (e0>>2) + q];
    *(float4*)&Cts[rr][q*4] = make_float4(bf2f(ct4.x),bf2f(ct4.y),bf2f(ct4.z),bf2f(ct4.w));
  }
  __syncthreads();
  int ty = tid>>4, tx = tid&15;              // 16 row-groups x 16 col-groups
  float acc[8][4];
  #pragma unroll
  for (int i=0;i<8;i++)
    #pragma unroll
    for (int j=0;j<4;j++) acc[i][j]=0.f;
  #pragma unroll 4
  for (int s=0;s<64;s++){
    float4 c4 = *(const float4*)&Cts[s][4*tx];
    #pragma unroll
    for (int i=0;i<8;i++){
      float hv = Hs[8*ty+i][s];
      acc[i][0]+=hv*c4.x; acc[i][1]+=hv*c4.y; acc[i][2]+=hv*c4.z; acc[i][3]+=hv*c4.w;
    }
  }
  float4 d4 = ((const float4*)(ws + WS_D))[(e0>>2) + tx];
  #pragma unroll
  for (int i=0;i<8;i++){
    int row = row0 + 8*ty + i;
    float4 x4v = reinterpret_cast<const float4*>(x + (size_t)row*EMB_ + e0)[tx];
    float4 o;
    o.x = acc[i][0] + d4.x*x4v.x;
    o.y = acc[i][1] + d4.y*x4v.y;
    o.z = acc[i][2] + d4.z*x4v.z;
    o.w = acc[i][3] + d4.w*x4v.w;
    ntstore(out + (size_t)row*EMB_ + e0 + 4*tx, o);
  }
}

extern "C" void kernel_launch(void* const* d_in, const int* in_sizes, int n_in,
                              void* d_out, int out_size, void* d_ws, size_t ws_size,
                              hipStream_t stream){
  const float* te  = (const float*)d_in[0];
  const float* x   = (const float*)d_in[1];
  const float* W1  = (const float*)d_in[2];
  const float* b1  = (const float*)d_in[3];
  const float* W2  = (const float*)d_in[4];
  const float* b2  = (const float*)d_in[5];
  const float* WA  = (const float*)d_in[6];
  const float* bA  = (const float*)d_in[7];
  const float* WB  = (const float*)d_in[8];
  const float* bB  = (const float*)d_in[9];
  const float* WC  = (const float*)d_in[10];
  const float* bC  = (const float*)d_in[11];
  const float* WD  = (const float*)d_in[12];
  const float* bD  = (const float*)d_in[13];
  const float* Wdl = (const float*)d_in[14];
  const float* bdl = (const float*)d_in[15];
  const float* MA  = (const float*)d_in[16];
  const float* mA  = (const float*)d_in[17];
  const float* MB  = (const float*)d_in[18];
  const float* mB  = (const float*)d_in[19];
  const float* MC  = (const float*)d_in[20];
  const float* mC  = (const float*)d_in[21];
  const float* MD  = (const float*)d_in[22];
  const float* mD  = (const float*)d_in[23];
  const float* Mdl = (const float*)d_in[24];
  const float* mdl = (const float*)d_in[25];
  float* ws  = (float*)d_ws;
  float* out = (float*)d_out;

  k_t1<<<8,64,0,stream>>>(te, W1, b1, ws);
  k_t2<<<8,512,0,stream>>>(W2, b2, ws);
  k_partial<<<1302,256,0,stream>>>(te, WB,MB, WC,MC, WD,MD, WA,MA, Wdl,Mdl, ws);
  k_finalize<<<130,256,0,stream>>>(bB,mB, bC,mC, bD,mD, bA,mA, bdl,mdl, ws);
  k_scan<<<256,256,0,stream>>>(x, ws);
  k_carry<<<1,256,0,stream>>>(ws);
  k_out<<<2048,256,0,stream>>>(x, ws, out);
}